// Round 6
// baseline (325.634 us; speedup 1.0000x reference)
//
#include <hip/hip_runtime.h>
#include <hip/hip_bf16.h>
#include <math.h>

typedef __hip_bfloat16 bf16;
typedef __bf16 nbf16;
typedef __bf16 bf16x8 __attribute__((ext_vector_type(8)));
typedef __bf16 bf16x4 __attribute__((ext_vector_type(4)));
typedef float f32x4 __attribute__((ext_vector_type(4)));

#define D_MODEL 1024
#define NHEAD   16
#define HDK     64
#define BATCH   2
#define SEQ     2048
#define QSZ     ((size_t)BATCH * SEQ * D_MODEL)
#define WSZ     ((size_t)D_MODEL * D_MODEL)

// ---------------------------------------------------------------------------
// Dtype auto-detect (unchanged, proven).
// ---------------------------------------------------------------------------
__global__ void detect_dtype(const unsigned short* __restrict__ x, int* flag) {
    __shared__ int cnt;
    if (threadIdx.x == 0) cnt = 0;
    __syncthreads();
    int local = 0;
    for (int i = threadIdx.x; i < 4096; i += 256) {
        const unsigned short v = x[i];
        const int e = (v >> 7) & 0xFF;
        if (v == 0 || (e >= 96 && e <= 141)) local++;
    }
    atomicAdd(&cnt, local);
    __syncthreads();
    if (threadIdx.x == 0) *flag = (cnt >= 3600) ? 1 : 0;
}

__device__ __forceinline__ float ldIn(const void* p, size_t i, int isbf16) {
    return isbf16 ? __bfloat162float(((const bf16*)p)[i])
                  : ((const float*)p)[i];
}

__device__ __forceinline__ void gload_lds16(const void* g, void* l) {
    __builtin_amdgcn_global_load_lds(
        (const __attribute__((address_space(1))) void*)g,
        (__attribute__((address_space(3))) void*)l, 16, 0, 0);
}

// ---------------------------------------------------------------------------
// Convert X and Y to bf16 in ONE launch (blocks 0..2047 -> X, rest -> Y).
// ---------------------------------------------------------------------------
__global__ void tobf16_xy(const void* __restrict__ X, const void* __restrict__ Y,
                          nbf16* __restrict__ Xb, nbf16* __restrict__ Yb,
                          const int* __restrict__ flagp) {
    const int flag = *flagp;
    const int half = (int)(QSZ / 2048);          // 2048 blocks per tensor
    const bool isX = blockIdx.x < half;
    const void* in = isX ? X : Y;
    nbf16* out     = isX ? Xb : Yb;
    const size_t i = ((size_t)(isX ? blockIdx.x : blockIdx.x - half) * 256 +
                      threadIdx.x) * 8;
    if (flag) {
        *(uint4*)(out + i) = *(const uint4*)((const nbf16*)in + i);
    } else {
        const float4 a = *(const float4*)((const float*)in + i);
        const float4 b = *(const float4*)((const float*)in + i + 4);
        bf16x8 v = {(nbf16)a.x, (nbf16)a.y, (nbf16)a.z, (nbf16)a.w,
                    (nbf16)b.x, (nbf16)b.y, (nbf16)b.z, (nbf16)b.w};
        *(bf16x8*)(out + i) = v;
    }
}

// ---------------------------------------------------------------------------
// Weight transpose, all 4 weights in ONE launch (z selects weight).
// W[k][n] (flag dtype) -> Wt[n][k] bf16.
// ---------------------------------------------------------------------------
__global__ void wtrans4(const void* __restrict__ qW, const void* __restrict__ kW,
                        const void* __restrict__ vW, const void* __restrict__ oW,
                        nbf16* __restrict__ Wt3, nbf16* __restrict__ Wto,
                        const int* __restrict__ flagp) {
    const int flag = *flagp;
    const int z = blockIdx.z;
    const void* W = (z == 0) ? qW : (z == 1) ? kW : (z == 2) ? vW : oW;
    nbf16* Wt = (z == 3) ? Wto : Wt3 + (size_t)z * WSZ;

    __shared__ float T[64][65];
    const int k0 = blockIdx.x * 64, n0 = blockIdx.y * 64;
    #pragma unroll
    for (int i = 0; i < 16; ++i) {
        const int idx = threadIdx.x + i * 256;
        const int r = idx >> 6, c = idx & 63;
        T[r][c] = ldIn(W, (size_t)(k0 + r) * D_MODEL + n0 + c, flag);
    }
    __syncthreads();
    #pragma unroll
    for (int i = 0; i < 16; ++i) {
        const int idx = threadIdx.x + i * 256;
        const int n = idx >> 6, k = idx & 63;
        Wt[(size_t)(n0 + n) * D_MODEL + k0 + k] = (nbf16)T[k][n];
    }
}

// ---------------------------------------------------------------------------
// 128x128 GEMM staging + K-loop (proven round 5).
// ---------------------------------------------------------------------------
#define STAGE128(Albuf, Blbuf, Aptr, Bptr, t)                                  \
{                                                                              \
    const int _k0 = (t) * 64;                                                  \
    _Pragma("unroll")                                                          \
    for (int i = 0; i < 4; ++i) {                                              \
        const int row = i * 32 + wid * 8 + (lane >> 3);                        \
        const int ss  = (lane & 7) ^ (row & 7);                                \
        gload_lds16((Aptr) + (size_t)row * D_MODEL + _k0 + ss * 8,             \
                    (nbf16*)(Albuf) + i * 2048 + wid * 512);                   \
        gload_lds16((Bptr) + (size_t)row * D_MODEL + _k0 + ss * 8,             \
                    (nbf16*)(Blbuf) + i * 2048 + wid * 512);                   \
    }                                                                          \
}

#define GEMM128_LOOP(Al, Bl)                                                   \
    const int NT = D_MODEL / 64;                                               \
    for (int t = 0; t < NT; ++t) {                                             \
        const int cur = t & 1;                                                 \
        if (t + 1 < NT)                                                        \
            STAGE128(&Al[cur ^ 1][0][0], &Bl[cur ^ 1][0][0], Am, Bm, t + 1);   \
        _Pragma("unroll")                                                      \
        for (int kk = 0; kk < 2; ++kk) {                                       \
            bf16x8 af[4], bfr[4];                                              \
            _Pragma("unroll")                                                  \
            for (int mi = 0; mi < 4; ++mi) {                                   \
                const int ar = wr * 64 + mi * 16 + l15;                        \
                const int sl = ((kk << 2) + lg) ^ (ar & 7);                    \
                af[mi] = *(const bf16x8*)((const nbf16*)&Al[cur][ar][0] + sl * 8); \
            }                                                                  \
            _Pragma("unroll")                                                  \
            for (int ni = 0; ni < 4; ++ni) {                                   \
                const int br = wc * 64 + ni * 16 + l15;                        \
                const int sl = ((kk << 2) + lg) ^ (br & 7);                    \
                bfr[ni] = *(const bf16x8*)((const nbf16*)&Bl[cur][br][0] + sl * 8); \
            }                                                                  \
            _Pragma("unroll")                                                  \
            for (int mi = 0; mi < 4; ++mi)                                     \
                _Pragma("unroll")                                              \
                for (int ni = 0; ni < 4; ++ni)                                 \
                    acc[mi][ni] = __builtin_amdgcn_mfma_f32_16x16x32_bf16(     \
                        af[mi], bfr[ni], acc[mi][ni], 0, 0, 0);                \
        }                                                                      \
        __syncthreads();                                                       \
    }

// ---------------------------------------------------------------------------
// Fused QKV projection, 128x128 tile (proven round 5).
// ---------------------------------------------------------------------------
__global__ __launch_bounds__(256, 2) void proj_qkv(
        const nbf16* __restrict__ Xb, const nbf16* __restrict__ Yb,
        const nbf16* __restrict__ Wt3,
        const void* __restrict__ qB, const void* __restrict__ kB,
        const void* __restrict__ vB,
        nbf16* __restrict__ outq, const int* __restrict__ flagp) {
    __shared__ nbf16 Al[2][128][64];
    __shared__ nbf16 Bl[2][128][64];

    const int flag = *flagp;
    const int tid  = threadIdx.x;
    const int wid  = tid >> 6;
    const int lane = tid & 63;
    const int l15  = lane & 15;
    const int lg   = lane >> 4;
    const int wr   = wid >> 1;
    const int wc   = wid & 1;

    const int id = blockIdx.x;
    const int sw = (id & 7) * 96 + (id >> 3);
    const int m0  = (sw & 31) * 128;
    const int ng0 = (sw >> 5) * 128;

    const nbf16* A  = (ng0 < D_MODEL) ? Yb : Xb;
    const nbf16* Bm = Wt3 + (size_t)ng0 * D_MODEL;
    const nbf16* Am = A + (size_t)m0 * D_MODEL;

    f32x4 acc[4][4];
    #pragma unroll
    for (int mi = 0; mi < 4; ++mi)
        #pragma unroll
        for (int ni = 0; ni < 4; ++ni) acc[mi][ni] = (f32x4){0.f, 0.f, 0.f, 0.f};

    STAGE128(&Al[0][0][0], &Bl[0][0][0], Am, Bm, 0);
    __syncthreads();

    GEMM128_LOOP(Al, Bl)

    #pragma unroll
    for (int ni = 0; ni < 4; ++ni) {
        const int n  = ng0 + wc * 64 + ni * 16 + l15;
        const int wh = n >> 10;
        const int nl = n & 1023;
        const void* bp = (wh == 0) ? qB : (wh == 1) ? kB : vB;
        const float bias = ldIn(bp, (size_t)nl, flag);
        nbf16* outp = outq + (size_t)wh * QSZ;
        #pragma unroll
        for (int mi = 0; mi < 4; ++mi) {
            #pragma unroll
            for (int r = 0; r < 4; ++r) {
                const int m = m0 + wr * 64 + mi * 16 + lg * 4 + r;
                const float v = acc[mi][ni][r] + bias;
                const int b = m >> 11, s = m & (SEQ - 1);
                const int h = nl >> 6,  d = nl & (HDK - 1);
                outp[(((size_t)(b * NHEAD + h)) * SEQ + s) * HDK + d] = (nbf16)v;
            }
        }
    }
}

// ---------------------------------------------------------------------------
// O projection, 128x128 tile (proven round 5).
// ---------------------------------------------------------------------------
__global__ __launch_bounds__(256, 2) void proj_o(
        const nbf16* __restrict__ A, const nbf16* __restrict__ Wt,
        const void* __restrict__ Braw, void* __restrict__ Cout,
        const int* __restrict__ flagp) {
    __shared__ nbf16 Al[2][128][64];
    __shared__ nbf16 Bl[2][128][64];

    const int flag = *flagp;
    const int tid  = threadIdx.x;
    const int wid  = tid >> 6;
    const int lane = tid & 63;
    const int l15  = lane & 15;
    const int lg   = lane >> 4;
    const int wr   = wid >> 1;
    const int wc   = wid & 1;

    const int id = blockIdx.x;
    const int sw = (id & 7) * 32 + (id >> 3);
    const int m0 = (sw >> 3) * 128;
    const int n0 = (sw & 7) * 128;

    const nbf16* Am = A + (size_t)m0 * D_MODEL;
    const nbf16* Bm = Wt + (size_t)n0 * D_MODEL;

    f32x4 acc[4][4];
    #pragma unroll
    for (int mi = 0; mi < 4; ++mi)
        #pragma unroll
        for (int ni = 0; ni < 4; ++ni) acc[mi][ni] = (f32x4){0.f, 0.f, 0.f, 0.f};

    STAGE128(&Al[0][0][0], &Bl[0][0][0], Am, Bm, 0);
    __syncthreads();

    GEMM128_LOOP(Al, Bl)

    #pragma unroll
    for (int ni = 0; ni < 4; ++ni) {
        const int n = n0 + wc * 64 + ni * 16 + l15;
        const float bias = ldIn(Braw, (size_t)n, flag);
        #pragma unroll
        for (int mi = 0; mi < 4; ++mi) {
            #pragma unroll
            for (int r = 0; r < 4; ++r) {
                const int m = m0 + wr * 64 + mi * 16 + lg * 4 + r;
                const float v = acc[mi][ni][r] + bias;
                if (flag) ((bf16*)Cout)[(size_t)m * D_MODEL + n] = __float2bfloat16(v);
                else      ((float*)Cout)[(size_t)m * D_MODEL + n] = v;
            }
        }
    }
}

// ---------------------------------------------------------------------------
// MFMA flash attention v3: occupancy-first.
// 64 q per block (wave = 16 q), grid 1024 = 4 blocks/CU (single pass).
// K read DIRECT from global (L2-resident 256KB/bh; same-bh blocks co-located
// per XCD by the swizzle) -- no KL staging, no DMA/barrier coupling.
// V staged in VT[2][64][72] (b32 conflict-free writes, round-4 proven).
// P via PB[4][16][72] b64 writes (round-3/4 proven).
// T5 setprio + T13 defer-max retained (round-5 proven).
// Softmax stats at lane l15; O rows q=lg*4+r -> shuffle alpha/lden (round 1).
// ---------------------------------------------------------------------------
__global__ __launch_bounds__(256, 4) void attn_mfma(
        const nbf16* __restrict__ qg, const nbf16* __restrict__ kg,
        const nbf16* __restrict__ vg, nbf16* __restrict__ cg) {
    __shared__ nbf16 VT[2][64][72];   // 18 KB
    __shared__ nbf16 PB[4][16][72];   //  9 KB   -> 27.6 KB total, 4+ blocks/CU

    const int tid  = threadIdx.x;
    const int wid  = tid >> 6;
    const int lane = tid & 63;
    const int l15  = lane & 15;
    const int lg   = lane >> 4;

    const int id = blockIdx.x;                 // 1024 blocks
    const int sw = (id & 7) * 128 + (id >> 3); // bijective XCD swizzle
    const int bh = sw >> 5;                    // 0..31
    const int qt = sw & 31;                    // 0..31

    const nbf16* qb = qg + (size_t)bh * SEQ * HDK;
    const nbf16* kb = kg + (size_t)bh * SEQ * HDK;
    const nbf16* vb = vg + (size_t)bh * SEQ * HDK;

    // Q fragments: wave's 16 q rows
    const int qbase = qt * 64 + wid * 16;
    const nbf16* qp = qb + (size_t)(qbase + l15) * HDK + lg * 8;
    const bf16x8 qf0 = *(const bf16x8*)qp;
    const bf16x8 qf1 = *(const bf16x8*)(qp + 32);

    // V staging map (round 4): thread covers 8 d x 2 kv, b32 packed writes
    const int g8 = (tid >> 5) * 8;
    const int p2 = (tid & 31) * 2;

    #define VLOAD(t)                                                           \
        a0 = *(const uint4*)(vb + (size_t)((t) * 64 + p2) * HDK + g8);         \
        a1 = *(const uint4*)(vb + (size_t)((t) * 64 + p2 + 1) * HDK + g8);

    #define VWRITE(buf)                                                        \
    {                                                                          \
        const unsigned short* e0 = (const unsigned short*)&a0;                 \
        const unsigned short* e1 = (const unsigned short*)&a1;                 \
        _Pragma("unroll")                                                      \
        for (int j = 0; j < 8; ++j)                                            \
            *(unsigned int*)&VT[buf][g8 + j][p2] =                             \
                (unsigned int)e0[j] | ((unsigned int)e1[j] << 16);             \
    }

    const float SC = 0.125f * 1.44269504088896340736f;

    // T13 defer-max (log2 domain, THR=8): skip O-rescale when tile max does
    // not exceed m2+8 for any q in the wave (P bounded by 2^8, bf16-safe).
    #define SOFTMAX(st, m2, lden, o, pbrow)                                    \
    do {                                                                       \
        _Pragma("unroll")                                                      \
        for (int s_ = 0; s_ < 4; ++s_)                                         \
            _Pragma("unroll")                                                  \
            for (int r = 0; r < 4; ++r) st[s_][r] *= SC;                       \
        float tmx[4];                                                          \
        _Pragma("unroll")                                                      \
        for (int s_ = 0; s_ < 4; ++s_)                                         \
            tmx[s_] = fmaxf(fmaxf(st[s_][0], st[s_][1]),                       \
                            fmaxf(st[s_][2], st[s_][3]));                      \
        float tm = fmaxf(fmaxf(tmx[0], tmx[1]), fmaxf(tmx[2], tmx[3]));        \
        tm = fmaxf(tm, __shfl_xor(tm, 16, 64));                                \
        tm = fmaxf(tm, __shfl_xor(tm, 32, 64));                                \
        const bool nresc = __all(tm - m2 <= 8.0f);                             \
        const float mref = nresc ? m2 : fmaxf(m2, tm);                         \
        float ts = 0.f;                                                        \
        _Pragma("unroll")                                                      \
        for (int s_ = 0; s_ < 4; ++s_) {                                       \
            const float p0 = exp2f(st[s_][0] - mref);                          \
            const float p1 = exp2f(st[s_][1] - mref);                          \
            const float p2_ = exp2f(st[s_][2] - mref);                         \
            const float p3 = exp2f(st[s_][3] - mref);                          \
            ts += (p0 + p1) + (p2_ + p3);                                      \
            bf16x4 pk = {(nbf16)p0, (nbf16)p1, (nbf16)p2_, (nbf16)p3};         \
            *(bf16x4*)((pbrow) + s_ * 16 + lg * 4) = pk;                       \
        }                                                                      \
        ts += __shfl_xor(ts, 16, 64);                                          \
        ts += __shfl_xor(ts, 32, 64);                                          \
        if (nresc) {                                                           \
            lden += ts;                                                        \
        } else {                                                               \
            const float alpha = exp2f(m2 - mref);                              \
            lden = lden * alpha + ts;                                          \
            m2 = mref;                                                         \
            float av[4];                                                       \
            _Pragma("unroll")                                                  \
            for (int r = 0; r < 4; ++r) av[r] = __shfl(alpha, lg * 4 + r, 64); \
            _Pragma("unroll")                                                  \
            for (int i = 0; i < 4; ++i)                                        \
                _Pragma("unroll")                                              \
                for (int r = 0; r < 4; ++r) o[i][r] *= av[r];                  \
        }                                                                      \
    } while (0)

    float m2 = -3.0e38f, lden = 0.f;
    f32x4 o[4];
    #pragma unroll
    for (int i = 0; i < 4; ++i) o[i] = (f32x4){0, 0, 0, 0};

    const int NT = SEQ / 64;   // 32

    {   // prologue: stage V tile 0
        uint4 a0, a1;
        VLOAD(0);
        VWRITE(0);
    }
    __syncthreads();

    for (int t = 0; t < NT; ++t) {
        const int cur = t & 1;
        uint4 a0, a1;
        if (t + 1 < NT) VLOAD(t + 1);   // prefetch next V into regs

        // ---- QK^T: K fragments direct from global (L2-resident) ----
        f32x4 st[4];
        const nbf16* kt = kb + (size_t)t * 64 * HDK;
        __builtin_amdgcn_s_setprio(1);
        #pragma unroll
        for (int sub = 0; sub < 4; ++sub) {
            const nbf16* kp = kt + (size_t)(sub * 16 + l15) * HDK + lg * 8;
            const bf16x8 kf0 = *(const bf16x8*)kp;
            const bf16x8 kf1 = *(const bf16x8*)(kp + 32);
            f32x4 a = (f32x4){0, 0, 0, 0};
            a = __builtin_amdgcn_mfma_f32_16x16x32_bf16(kf0, qf0, a, 0, 0, 0);
            a = __builtin_amdgcn_mfma_f32_16x16x32_bf16(kf1, qf1, a, 0, 0, 0);
            st[sub] = a;
        }
        __builtin_amdgcn_s_setprio(0);

        SOFTMAX(st, m2, lden, o, &PB[wid][l15][0]);

        // wave-local fence: P ds_writes complete before P ds_reads
        __asm__ volatile("s_waitcnt lgkmcnt(0)" ::: "memory");

        // ---- PV ----
        const bf16x8 pf0 = *(const bf16x8*)&PB[wid][l15][lg * 8];
        const bf16x8 pf1 = *(const bf16x8*)&PB[wid][l15][lg * 8 + 32];
        __builtin_amdgcn_s_setprio(1);
        #pragma unroll
        for (int db = 0; db < 4; ++db) {
            const bf16x8 vf0 = *(const bf16x8*)&VT[cur][db * 16 + l15][lg * 8];
            const bf16x8 vf1 = *(const bf16x8*)&VT[cur][db * 16 + l15][lg * 8 + 32];
            o[db] = __builtin_amdgcn_mfma_f32_16x16x32_bf16(pf0, vf0, o[db], 0, 0, 0);
            o[db] = __builtin_amdgcn_mfma_f32_16x16x32_bf16(pf1, vf1, o[db], 0, 0, 0);
        }
        __builtin_amdgcn_s_setprio(0);

        if (t + 1 < NT) VWRITE(cur ^ 1);
        __syncthreads();   // V/P writes drained; tile handoff
    }

    // ---- epilogue: normalize + write concat (B,S,D) bf16 ----
    const int b = bh >> 4, h = bh & 15;
    float invd[4];
    #pragma unroll
    for (int r = 0; r < 4; ++r)
        invd[r] = 1.f / __shfl(lden, lg * 4 + r, 64);
    #pragma unroll
    for (int db = 0; db < 4; ++db) {
        #pragma unroll
        for (int r = 0; r < 4; ++r) {
            const int qr2 = qbase + lg * 4 + r;
            cg[((size_t)(b * SEQ + qr2)) * D_MODEL + h * HDK + db * 16 + l15] =
                (nbf16)(o[db][r] * invd[r]);
        }
    }
    #undef VLOAD
    #undef VWRITE
    #undef SOFTMAX
}

// ---------------------------------------------------------------------------
extern "C" void kernel_launch(void* const* d_in, const int* in_sizes, int n_in,
                              void* d_out, int out_size, void* d_ws, size_t ws_size,
                              hipStream_t stream) {
    const void* X  = d_in[0];
    const void* Y  = d_in[1];
    const void* qW = d_in[2];
    const void* qB = d_in[3];
    const void* kW = d_in[4];
    const void* kB = d_in[5];
    const void* vW = d_in[6];
    const void* vB = d_in[7];
    const void* oW = d_in[8];
    const void* oB = d_in[9];

    nbf16* ws = (nbf16*)d_ws;
    nbf16* qbuf = ws;                  // (B,H,S,dk) bf16; k,v contiguous after
    nbf16* kbuf = qbuf + QSZ;
    nbf16* vbuf = kbuf + QSZ;
    nbf16* cbuf = vbuf + QSZ;          // concat (B,S,D) bf16
    nbf16* Xb   = cbuf + QSZ;
    nbf16* Yb   = Xb + QSZ;
    nbf16* Wt3  = Yb + QSZ;            // [3072][1024] q|k|v
    nbf16* Wto  = Wt3 + 3 * WSZ;
    int*   flag = (int*)(Wto + WSZ);

    detect_dtype<<<1, 256, 0, stream>>>((const unsigned short*)X, flag);

    tobf16_xy<<<(int)(2 * (QSZ / 2048)), 256, 0, stream>>>(X, Y, Xb, Yb, flag);

    wtrans4<<<dim3(16, 16, 4), 256, 0, stream>>>(qW, kW, vW, oW, Wt3, Wto, flag);

    proj_qkv<<<768, 256, 0, stream>>>(Xb, Yb, Wt3, qB, kB, vB, qbuf, flag);

    attn_mfma<<<1024, 256, 0, stream>>>(qbuf, kbuf, vbuf, cbuf);

    proj_o<<<256, 256, 0, stream>>>(cbuf, Wto, oB, d_out, flag);
}

// Round 7
// 285.478 us; speedup vs baseline: 1.1407x; 1.1407x over previous
//
#include <hip/hip_runtime.h>
#include <hip/hip_bf16.h>
#include <math.h>

typedef __hip_bfloat16 bf16;
typedef __bf16 nbf16;
typedef __bf16 bf16x8 __attribute__((ext_vector_type(8)));
typedef __bf16 bf16x4 __attribute__((ext_vector_type(4)));
typedef float f32x4 __attribute__((ext_vector_type(4)));

#define D_MODEL 1024
#define NHEAD   16
#define HDK     64
#define BATCH   2
#define SEQ     2048
#define QSZ     ((size_t)BATCH * SEQ * D_MODEL)
#define WSZ     ((size_t)D_MODEL * D_MODEL)

// ---------------------------------------------------------------------------
// Dtype auto-detect (unchanged, proven).
// ---------------------------------------------------------------------------
__global__ void detect_dtype(const unsigned short* __restrict__ x, int* flag) {
    __shared__ int cnt;
    if (threadIdx.x == 0) cnt = 0;
    __syncthreads();
    int local = 0;
    for (int i = threadIdx.x; i < 4096; i += 256) {
        const unsigned short v = x[i];
        const int e = (v >> 7) & 0xFF;
        if (v == 0 || (e >= 96 && e <= 141)) local++;
    }
    atomicAdd(&cnt, local);
    __syncthreads();
    if (threadIdx.x == 0) *flag = (cnt >= 3600) ? 1 : 0;
}

__device__ __forceinline__ float ldIn(const void* p, size_t i, int isbf16) {
    return isbf16 ? __bfloat162float(((const bf16*)p)[i])
                  : ((const float*)p)[i];
}

__device__ __forceinline__ void gload_lds16(const void* g, void* l) {
    __builtin_amdgcn_global_load_lds(
        (const __attribute__((address_space(1))) void*)g,
        (__attribute__((address_space(3))) void*)l, 16, 0, 0);
}

// ---------------------------------------------------------------------------
// Convert X and Y to bf16 in ONE launch (proven round 6).
// ---------------------------------------------------------------------------
__global__ void tobf16_xy(const void* __restrict__ X, const void* __restrict__ Y,
                          nbf16* __restrict__ Xb, nbf16* __restrict__ Yb,
                          const int* __restrict__ flagp) {
    const int flag = *flagp;
    const int half = (int)(QSZ / 2048);
    const bool isX = blockIdx.x < half;
    const void* in = isX ? X : Y;
    nbf16* out     = isX ? Xb : Yb;
    const size_t i = ((size_t)(isX ? blockIdx.x : blockIdx.x - half) * 256 +
                      threadIdx.x) * 8;
    if (flag) {
        *(uint4*)(out + i) = *(const uint4*)((const nbf16*)in + i);
    } else {
        const float4 a = *(const float4*)((const float*)in + i);
        const float4 b = *(const float4*)((const float*)in + i + 4);
        bf16x8 v = {(nbf16)a.x, (nbf16)a.y, (nbf16)a.z, (nbf16)a.w,
                    (nbf16)b.x, (nbf16)b.y, (nbf16)b.z, (nbf16)b.w};
        *(bf16x8*)(out + i) = v;
    }
}

// ---------------------------------------------------------------------------
// Weight transpose, all 4 weights in ONE launch (proven round 6).
// ---------------------------------------------------------------------------
__global__ void wtrans4(const void* __restrict__ qW, const void* __restrict__ kW,
                        const void* __restrict__ vW, const void* __restrict__ oW,
                        nbf16* __restrict__ Wt3, nbf16* __restrict__ Wto,
                        const int* __restrict__ flagp) {
    const int flag = *flagp;
    const int z = blockIdx.z;
    const void* W = (z == 0) ? qW : (z == 1) ? kW : (z == 2) ? vW : oW;
    nbf16* Wt = (z == 3) ? Wto : Wt3 + (size_t)z * WSZ;

    __shared__ float T[64][65];
    const int k0 = blockIdx.x * 64, n0 = blockIdx.y * 64;
    #pragma unroll
    for (int i = 0; i < 16; ++i) {
        const int idx = threadIdx.x + i * 256;
        const int r = idx >> 6, c = idx & 63;
        T[r][c] = ldIn(W, (size_t)(k0 + r) * D_MODEL + n0 + c, flag);
    }
    __syncthreads();
    #pragma unroll
    for (int i = 0; i < 16; ++i) {
        const int idx = threadIdx.x + i * 256;
        const int n = idx >> 6, k = idx & 63;
        Wt[(size_t)(n0 + n) * D_MODEL + k0 + k] = (nbf16)T[k][n];
    }
}

// ---------------------------------------------------------------------------
// 128x128 GEMM staging + K-loop (proven rounds 5-6).
// ---------------------------------------------------------------------------
#define STAGE128(Albuf, Blbuf, Aptr, Bptr, t)                                  \
{                                                                              \
    const int _k0 = (t) * 64;                                                  \
    _Pragma("unroll")                                                          \
    for (int i = 0; i < 4; ++i) {                                              \
        const int row = i * 32 + wid * 8 + (lane >> 3);                        \
        const int ss  = (lane & 7) ^ (row & 7);                                \
        gload_lds16((Aptr) + (size_t)row * D_MODEL + _k0 + ss * 8,             \
                    (nbf16*)(Albuf) + i * 2048 + wid * 512);                   \
        gload_lds16((Bptr) + (size_t)row * D_MODEL + _k0 + ss * 8,             \
                    (nbf16*)(Blbuf) + i * 2048 + wid * 512);                   \
    }                                                                          \
}

#define GEMM128_LOOP(Al, Bl)                                                   \
    const int NT = D_MODEL / 64;                                               \
    for (int t = 0; t < NT; ++t) {                                             \
        const int cur = t & 1;                                                 \
        if (t + 1 < NT)                                                        \
            STAGE128(&Al[cur ^ 1][0][0], &Bl[cur ^ 1][0][0], Am, Bm, t + 1);   \
        _Pragma("unroll")                                                      \
        for (int kk = 0; kk < 2; ++kk) {                                       \
            bf16x8 af[4], bfr[4];                                              \
            _Pragma("unroll")                                                  \
            for (int mi = 0; mi < 4; ++mi) {                                   \
                const int ar = wr * 64 + mi * 16 + l15;                        \
                const int sl = ((kk << 2) + lg) ^ (ar & 7);                    \
                af[mi] = *(const bf16x8*)((const nbf16*)&Al[cur][ar][0] + sl * 8); \
            }                                                                  \
            _Pragma("unroll")                                                  \
            for (int ni = 0; ni < 4; ++ni) {                                   \
                const int br = wc * 64 + ni * 16 + l15;                        \
                const int sl = ((kk << 2) + lg) ^ (br & 7);                    \
                bfr[ni] = *(const bf16x8*)((const nbf16*)&Bl[cur][br][0] + sl * 8); \
            }                                                                  \
            _Pragma("unroll")                                                  \
            for (int mi = 0; mi < 4; ++mi)                                     \
                _Pragma("unroll")                                              \
                for (int ni = 0; ni < 4; ++ni)                                 \
                    acc[mi][ni] = __builtin_amdgcn_mfma_f32_16x16x32_bf16(     \
                        af[mi], bfr[ni], acc[mi][ni], 0, 0, 0);                \
        }                                                                      \
        __syncthreads();                                                       \
    }

// ---------------------------------------------------------------------------
// Fused QKV projection, 128x128 tile (proven rounds 5-6).
// ---------------------------------------------------------------------------
__global__ __launch_bounds__(256, 2) void proj_qkv(
        const nbf16* __restrict__ Xb, const nbf16* __restrict__ Yb,
        const nbf16* __restrict__ Wt3,
        const void* __restrict__ qB, const void* __restrict__ kB,
        const void* __restrict__ vB,
        nbf16* __restrict__ outq, const int* __restrict__ flagp) {
    __shared__ nbf16 Al[2][128][64];
    __shared__ nbf16 Bl[2][128][64];

    const int flag = *flagp;
    const int tid  = threadIdx.x;
    const int wid  = tid >> 6;
    const int lane = tid & 63;
    const int l15  = lane & 15;
    const int lg   = lane >> 4;
    const int wr   = wid >> 1;
    const int wc   = wid & 1;

    const int id = blockIdx.x;
    const int sw = (id & 7) * 96 + (id >> 3);
    const int m0  = (sw & 31) * 128;
    const int ng0 = (sw >> 5) * 128;

    const nbf16* A  = (ng0 < D_MODEL) ? Yb : Xb;
    const nbf16* Bm = Wt3 + (size_t)ng0 * D_MODEL;
    const nbf16* Am = A + (size_t)m0 * D_MODEL;

    f32x4 acc[4][4];
    #pragma unroll
    for (int mi = 0; mi < 4; ++mi)
        #pragma unroll
        for (int ni = 0; ni < 4; ++ni) acc[mi][ni] = (f32x4){0.f, 0.f, 0.f, 0.f};

    STAGE128(&Al[0][0][0], &Bl[0][0][0], Am, Bm, 0);
    __syncthreads();

    GEMM128_LOOP(Al, Bl)

    #pragma unroll
    for (int ni = 0; ni < 4; ++ni) {
        const int n  = ng0 + wc * 64 + ni * 16 + l15;
        const int wh = n >> 10;
        const int nl = n & 1023;
        const void* bp = (wh == 0) ? qB : (wh == 1) ? kB : vB;
        const float bias = ldIn(bp, (size_t)nl, flag);
        nbf16* outp = outq + (size_t)wh * QSZ;
        #pragma unroll
        for (int mi = 0; mi < 4; ++mi) {
            #pragma unroll
            for (int r = 0; r < 4; ++r) {
                const int m = m0 + wr * 64 + mi * 16 + lg * 4 + r;
                const float v = acc[mi][ni][r] + bias;
                const int b = m >> 11, s = m & (SEQ - 1);
                const int h = nl >> 6,  d = nl & (HDK - 1);
                outp[(((size_t)(b * NHEAD + h)) * SEQ + s) * HDK + d] = (nbf16)v;
            }
        }
    }
}

// ---------------------------------------------------------------------------
// O projection, 128x128 tile (proven rounds 5-6).
// ---------------------------------------------------------------------------
__global__ __launch_bounds__(256, 2) void proj_o(
        const nbf16* __restrict__ A, const nbf16* __restrict__ Wt,
        const void* __restrict__ Braw, void* __restrict__ Cout,
        const int* __restrict__ flagp) {
    __shared__ nbf16 Al[2][128][64];
    __shared__ nbf16 Bl[2][128][64];

    const int flag = *flagp;
    const int tid  = threadIdx.x;
    const int wid  = tid >> 6;
    const int lane = tid & 63;
    const int l15  = lane & 15;
    const int lg   = lane >> 4;
    const int wr   = wid >> 1;
    const int wc   = wid & 1;

    const int id = blockIdx.x;
    const int sw = (id & 7) * 32 + (id >> 3);
    const int m0 = (sw >> 3) * 128;
    const int n0 = (sw & 7) * 128;

    const nbf16* Am = A + (size_t)m0 * D_MODEL;
    const nbf16* Bm = Wt + (size_t)n0 * D_MODEL;

    f32x4 acc[4][4];
    #pragma unroll
    for (int mi = 0; mi < 4; ++mi)
        #pragma unroll
        for (int ni = 0; ni < 4; ++ni) acc[mi][ni] = (f32x4){0.f, 0.f, 0.f, 0.f};

    STAGE128(&Al[0][0][0], &Bl[0][0][0], Am, Bm, 0);
    __syncthreads();

    GEMM128_LOOP(Al, Bl)

    #pragma unroll
    for (int ni = 0; ni < 4; ++ni) {
        const int n = n0 + wc * 64 + ni * 16 + l15;
        const float bias = ldIn(Braw, (size_t)n, flag);
        #pragma unroll
        for (int mi = 0; mi < 4; ++mi) {
            #pragma unroll
            for (int r = 0; r < 4; ++r) {
                const int m = m0 + wr * 64 + mi * 16 + lg * 4 + r;
                const float v = acc[mi][ni][r] + bias;
                if (flag) ((bf16*)Cout)[(size_t)m * D_MODEL + n] = __float2bfloat16(v);
                else      ((float*)Cout)[(size_t)m * D_MODEL + n] = v;
            }
        }
    }
}

// ---------------------------------------------------------------------------
// MFMA flash attention v4 (= proven round-5 32q/wave structure, improved):
// - 32 q per wave (two 16-q frags), block 128 q, grid 512 (r4/r5 proven ladder:
//   16q=162us, 32q=88.5us -- q-amortization dominates).
// - K read DIRECT from global (r3/r6 proven equivalent to staging); KL buffer
//   removed -> LDS 36KB -> 4 blocks/CU (launch_bounds(256,4)).
// - Q pre-scaled by 0.125*log2e at load (kills 32 v_mul/tile/wave).
// - lden via ones-MFMA: osum=mfma(pf,ones,osum) -- denominator lands in the o[]
//   lane layout (no sum-adds, no shfl_xor, no epilogue lden shuffle).
// - T5 setprio + T13 defer-max retained; round-1 alpha lane-remap rule obeyed.
// ---------------------------------------------------------------------------
__global__ __launch_bounds__(256, 4) void attn_mfma(
        const nbf16* __restrict__ qg, const nbf16* __restrict__ kg,
        const nbf16* __restrict__ vg, nbf16* __restrict__ cg) {
    __shared__ nbf16 VT[2][64][72];   // 18 KB
    __shared__ nbf16 PB[4][32][72];   // 18 KB -> 36 KB total, 4 blocks/CU

    const int tid  = threadIdx.x;
    const int wid  = tid >> 6;
    const int lane = tid & 63;
    const int l15  = lane & 15;
    const int lg   = lane >> 4;

    const int id = blockIdx.x;                // 512 blocks
    const int sw = (id & 7) * 64 + (id >> 3); // bijective XCD swizzle
    const int bh = sw >> 4;                   // 0..31 (4 bh per XCD chunk)
    const int qt = sw & 15;                   // 0..15

    const nbf16* qb = qg + (size_t)bh * SEQ * HDK;
    const nbf16* kb = kg + (size_t)bh * SEQ * HDK;
    const nbf16* vb = vg + (size_t)bh * SEQ * HDK;

    const float SCf = 0.125f * 1.44269504088896340736f;

    // Q frags, pre-scaled by SCf (one extra bf16 rounding, within tolerance)
    const int qbase = qt * 128 + wid * 32;
    const nbf16* qpA = qb + (size_t)(qbase + l15) * HDK + lg * 8;
    const nbf16* qpB = qpA + 16 * HDK;
    bf16x8 qfA0 = *(const bf16x8*)qpA;
    bf16x8 qfA1 = *(const bf16x8*)(qpA + 32);
    bf16x8 qfB0 = *(const bf16x8*)qpB;
    bf16x8 qfB1 = *(const bf16x8*)(qpB + 32);
    #pragma unroll
    for (int j = 0; j < 8; ++j) {
        qfA0[j] = (nbf16)((float)qfA0[j] * SCf);
        qfA1[j] = (nbf16)((float)qfA1[j] * SCf);
        qfB0[j] = (nbf16)((float)qfB0[j] * SCf);
        qfB1[j] = (nbf16)((float)qfB1[j] * SCf);
    }

    // ones B-frag for the denominator MFMA (register constant, no LDS)
    const bf16x8 ones = {(nbf16)1.f, (nbf16)1.f, (nbf16)1.f, (nbf16)1.f,
                         (nbf16)1.f, (nbf16)1.f, (nbf16)1.f, (nbf16)1.f};

    // V staging map (r4 proven): thread covers 8 d x 2 kv, b32 packed writes
    const int g8 = (tid >> 5) * 8;
    const int p2 = (tid & 31) * 2;

    #define VLOAD(t)                                                           \
        a0 = *(const uint4*)(vb + (size_t)((t) * 64 + p2) * HDK + g8);         \
        a1 = *(const uint4*)(vb + (size_t)((t) * 64 + p2 + 1) * HDK + g8);

    #define VWRITE(buf)                                                        \
    {                                                                          \
        const unsigned short* e0 = (const unsigned short*)&a0;                 \
        const unsigned short* e1 = (const unsigned short*)&a1;                 \
        _Pragma("unroll")                                                      \
        for (int j = 0; j < 8; ++j)                                            \
            *(unsigned int*)&VT[buf][g8 + j][p2] =                             \
                (unsigned int)e0[j] | ((unsigned int)e1[j] << 16);             \
    }

    // T13 defer-max (log2 domain, THR=8). Scores arrive pre-scaled (Q*SCf).
    // osum (denominator) is rescaled alongside o; its accumulation happens in
    // the PV section via mfma(pf, ones, osum).
    #define SOFTMAX(st, m2, o, osum, pbrow)                                    \
    do {                                                                       \
        float tmx[4];                                                          \
        _Pragma("unroll")                                                      \
        for (int s_ = 0; s_ < 4; ++s_)                                         \
            tmx[s_] = fmaxf(fmaxf(st[s_][0], st[s_][1]),                       \
                            fmaxf(st[s_][2], st[s_][3]));                      \
        float tm = fmaxf(fmaxf(tmx[0], tmx[1]), fmaxf(tmx[2], tmx[3]));        \
        tm = fmaxf(tm, __shfl_xor(tm, 16, 64));                                \
        tm = fmaxf(tm, __shfl_xor(tm, 32, 64));                                \
        const bool nresc = __all(tm - m2 <= 8.0f);                             \
        const float mref = nresc ? m2 : fmaxf(m2, tm);                         \
        _Pragma("unroll")                                                      \
        for (int s_ = 0; s_ < 4; ++s_) {                                       \
            const float p0 = exp2f(st[s_][0] - mref);                          \
            const float p1 = exp2f(st[s_][1] - mref);                          \
            const float p2_ = exp2f(st[s_][2] - mref);                         \
            const float p3 = exp2f(st[s_][3] - mref);                          \
            bf16x4 pk = {(nbf16)p0, (nbf16)p1, (nbf16)p2_, (nbf16)p3};         \
            *(bf16x4*)((pbrow) + s_ * 16 + lg * 4) = pk;                       \
        }                                                                      \
        if (!nresc) {                                                          \
            const float alpha = exp2f(m2 - mref);                              \
            m2 = mref;                                                         \
            float av[4];                                                       \
            _Pragma("unroll")                                                  \
            for (int r = 0; r < 4; ++r) av[r] = __shfl(alpha, lg * 4 + r, 64); \
            _Pragma("unroll")                                                  \
            for (int i = 0; i < 4; ++i)                                        \
                _Pragma("unroll")                                              \
                for (int r = 0; r < 4; ++r) o[i][r] *= av[r];                  \
            _Pragma("unroll")                                                  \
            for (int r = 0; r < 4; ++r) osum[r] *= av[r];                      \
        }                                                                      \
    } while (0)

    float m2A = -3.0e38f, m2B = -3.0e38f;
    f32x4 oA[4], oB[4], osumA, osumB;
    #pragma unroll
    for (int i = 0; i < 4; ++i) { oA[i] = (f32x4){0,0,0,0}; oB[i] = (f32x4){0,0,0,0}; }
    osumA = (f32x4){0, 0, 0, 0};
    osumB = (f32x4){0, 0, 0, 0};

    const int NT = SEQ / 64;   // 32

    {   // prologue: stage V tile 0
        uint4 a0, a1;
        VLOAD(0);
        VWRITE(0);
    }
    __syncthreads();

    for (int t = 0; t < NT; ++t) {
        const int cur = t & 1;
        uint4 a0, a1;
        if (t + 1 < NT) VLOAD(t + 1);   // prefetch next V into regs

        // ---- QK^T: K direct from global (L2-resident) ----
        f32x4 stA[4], stB[4];
        const nbf16* kt = kb + (size_t)t * 64 * HDK;
        __builtin_amdgcn_s_setprio(1);
        #pragma unroll
        for (int sub = 0; sub < 4; ++sub) {
            const nbf16* kp = kt + (size_t)(sub * 16 + l15) * HDK + lg * 8;
            const bf16x8 kf0 = *(const bf16x8*)kp;
            const bf16x8 kf1 = *(const bf16x8*)(kp + 32);
            f32x4 a = (f32x4){0, 0, 0, 0};
            a = __builtin_amdgcn_mfma_f32_16x16x32_bf16(kf0, qfA0, a, 0, 0, 0);
            a = __builtin_amdgcn_mfma_f32_16x16x32_bf16(kf1, qfA1, a, 0, 0, 0);
            stA[sub] = a;
            f32x4 b = (f32x4){0, 0, 0, 0};
            b = __builtin_amdgcn_mfma_f32_16x16x32_bf16(kf0, qfB0, b, 0, 0, 0);
            b = __builtin_amdgcn_mfma_f32_16x16x32_bf16(kf1, qfB1, b, 0, 0, 0);
            stB[sub] = b;
        }
        __builtin_amdgcn_s_setprio(0);

        SOFTMAX(stA, m2A, oA, osumA, &PB[wid][l15][0]);
        SOFTMAX(stB, m2B, oB, osumB, &PB[wid][16 + l15][0]);

        // wave-local fence: P ds_writes complete before P ds_reads
        __asm__ volatile("s_waitcnt lgkmcnt(0)" ::: "memory");

        // ---- PV + denominator MFMA ----
        const bf16x8 pfA0 = *(const bf16x8*)&PB[wid][l15][lg * 8];
        const bf16x8 pfA1 = *(const bf16x8*)&PB[wid][l15][lg * 8 + 32];
        const bf16x8 pfB0 = *(const bf16x8*)&PB[wid][16 + l15][lg * 8];
        const bf16x8 pfB1 = *(const bf16x8*)&PB[wid][16 + l15][lg * 8 + 32];
        __builtin_amdgcn_s_setprio(1);
        #pragma unroll
        for (int db = 0; db < 4; ++db) {
            const bf16x8 vf0 = *(const bf16x8*)&VT[cur][db * 16 + l15][lg * 8];
            const bf16x8 vf1 = *(const bf16x8*)&VT[cur][db * 16 + l15][lg * 8 + 32];
            oA[db] = __builtin_amdgcn_mfma_f32_16x16x32_bf16(pfA0, vf0, oA[db], 0, 0, 0);
            oA[db] = __builtin_amdgcn_mfma_f32_16x16x32_bf16(pfA1, vf1, oA[db], 0, 0, 0);
            oB[db] = __builtin_amdgcn_mfma_f32_16x16x32_bf16(pfB0, vf0, oB[db], 0, 0, 0);
            oB[db] = __builtin_amdgcn_mfma_f32_16x16x32_bf16(pfB1, vf1, oB[db], 0, 0, 0);
        }
        osumA = __builtin_amdgcn_mfma_f32_16x16x32_bf16(pfA0, ones, osumA, 0, 0, 0);
        osumA = __builtin_amdgcn_mfma_f32_16x16x32_bf16(pfA1, ones, osumA, 0, 0, 0);
        osumB = __builtin_amdgcn_mfma_f32_16x16x32_bf16(pfB0, ones, osumB, 0, 0, 0);
        osumB = __builtin_amdgcn_mfma_f32_16x16x32_bf16(pfB1, ones, osumB, 0, 0, 0);
        __builtin_amdgcn_s_setprio(0);

        if (t + 1 < NT) VWRITE(cur ^ 1);
        __syncthreads();   // V/P writes drained; tile handoff
    }

    // ---- epilogue: osum is already in the o[] lane layout (no shuffle) ----
    const int b = bh >> 4, h = bh & 15;
    #pragma unroll
    for (int db = 0; db < 4; ++db) {
        #pragma unroll
        for (int r = 0; r < 4; ++r) {
            const int qA = qbase + lg * 4 + r;
            cg[((size_t)(b * SEQ + qA)) * D_MODEL + h * HDK + db * 16 + l15] =
                (nbf16)(oA[db][r] / osumA[r]);
            const int qB_ = qbase + 16 + lg * 4 + r;
            cg[((size_t)(b * SEQ + qB_)) * D_MODEL + h * HDK + db * 16 + l15] =
                (nbf16)(oB[db][r] / osumB[r]);
        }
    }
    #undef VLOAD
    #undef VWRITE
    #undef SOFTMAX
}

// ---------------------------------------------------------------------------
extern "C" void kernel_launch(void* const* d_in, const int* in_sizes, int n_in,
                              void* d_out, int out_size, void* d_ws, size_t ws_size,
                              hipStream_t stream) {
    const void* X  = d_in[0];
    const void* Y  = d_in[1];
    const void* qW = d_in[2];
    const void* qB = d_in[3];
    const void* kW = d_in[4];
    const void* kB = d_in[5];
    const void* vW = d_in[6];
    const void* vB = d_in[7];
    const void* oW = d_in[8];
    const void* oB = d_in[9];

    nbf16* ws = (nbf16*)d_ws;
    nbf16* qbuf = ws;                  // (B,H,S,dk) bf16; k,v contiguous after
    nbf16* kbuf = qbuf + QSZ;
    nbf16* vbuf = kbuf + QSZ;
    nbf16* cbuf = vbuf + QSZ;          // concat (B,S,D) bf16
    nbf16* Xb   = cbuf + QSZ;
    nbf16* Yb   = Xb + QSZ;
    nbf16* Wt3  = Yb + QSZ;            // [3072][1024] q|k|v
    nbf16* Wto  = Wt3 + 3 * WSZ;
    int*   flag = (int*)(Wto + WSZ);

    detect_dtype<<<1, 256, 0, stream>>>((const unsigned short*)X, flag);

    tobf16_xy<<<(int)(2 * (QSZ / 2048)), 256, 0, stream>>>(X, Y, Xb, Yb, flag);

    wtrans4<<<dim3(16, 16, 4), 256, 0, stream>>>(qW, kW, vW, oW, Wt3, Wto, flag);

    proj_qkv<<<768, 256, 0, stream>>>(Xb, Yb, Wt3, qB, kB, vB, qbuf, flag);

    attn_mfma<<<512, 256, 0, stream>>>(qbuf, kbuf, vbuf, cbuf);

    proj_o<<<256, 256, 0, stream>>>(cbuf, Wto, oB, d_out, flag);
}

// Round 8
// 252.540 us; speedup vs baseline: 1.2894x; 1.1304x over previous
//
#include <hip/hip_runtime.h>
#include <hip/hip_bf16.h>
#include <math.h>

typedef __hip_bfloat16 bf16;
typedef __bf16 nbf16;
typedef __bf16 bf16x8 __attribute__((ext_vector_type(8)));
typedef __bf16 bf16x4 __attribute__((ext_vector_type(4)));
typedef float f32x4 __attribute__((ext_vector_type(4)));

#define D_MODEL 1024
#define NHEAD   16
#define HDK     64
#define BATCH   2
#define SEQ     2048
#define QSZ     ((size_t)BATCH * SEQ * D_MODEL)
#define WSZ     ((size_t)D_MODEL * D_MODEL)

// ---------------------------------------------------------------------------
// Dtype auto-detect (unchanged, proven).
// ---------------------------------------------------------------------------
__global__ void detect_dtype(const unsigned short* __restrict__ x, int* flag) {
    __shared__ int cnt;
    if (threadIdx.x == 0) cnt = 0;
    __syncthreads();
    int local = 0;
    for (int i = threadIdx.x; i < 4096; i += 256) {
        const unsigned short v = x[i];
        const int e = (v >> 7) & 0xFF;
        if (v == 0 || (e >= 96 && e <= 141)) local++;
    }
    atomicAdd(&cnt, local);
    __syncthreads();
    if (threadIdx.x == 0) *flag = (cnt >= 3600) ? 1 : 0;
}

__device__ __forceinline__ float ldIn(const void* p, size_t i, int isbf16) {
    return isbf16 ? __bfloat162float(((const bf16*)p)[i])
                  : ((const float*)p)[i];
}

__device__ __forceinline__ void gload_lds16(const void* g, void* l) {
    __builtin_amdgcn_global_load_lds(
        (const __attribute__((address_space(1))) void*)g,
        (__attribute__((address_space(3))) void*)l, 16, 0, 0);
}

// ---------------------------------------------------------------------------
// Convert X and Y to bf16 in ONE launch (proven round 6).
// ---------------------------------------------------------------------------
__global__ void tobf16_xy(const void* __restrict__ X, const void* __restrict__ Y,
                          nbf16* __restrict__ Xb, nbf16* __restrict__ Yb,
                          const int* __restrict__ flagp) {
    const int flag = *flagp;
    const int half = (int)(QSZ / 2048);
    const bool isX = blockIdx.x < half;
    const void* in = isX ? X : Y;
    nbf16* out     = isX ? Xb : Yb;
    const size_t i = ((size_t)(isX ? blockIdx.x : blockIdx.x - half) * 256 +
                      threadIdx.x) * 8;
    if (flag) {
        *(uint4*)(out + i) = *(const uint4*)((const nbf16*)in + i);
    } else {
        const float4 a = *(const float4*)((const float*)in + i);
        const float4 b = *(const float4*)((const float*)in + i + 4);
        bf16x8 v = {(nbf16)a.x, (nbf16)a.y, (nbf16)a.z, (nbf16)a.w,
                    (nbf16)b.x, (nbf16)b.y, (nbf16)b.z, (nbf16)b.w};
        *(bf16x8*)(out + i) = v;
    }
}

// ---------------------------------------------------------------------------
// Weight transpose, all 4 weights in ONE launch (proven round 6).
// ---------------------------------------------------------------------------
__global__ void wtrans4(const void* __restrict__ qW, const void* __restrict__ kW,
                        const void* __restrict__ vW, const void* __restrict__ oW,
                        nbf16* __restrict__ Wt3, nbf16* __restrict__ Wto,
                        const int* __restrict__ flagp) {
    const int flag = *flagp;
    const int z = blockIdx.z;
    const void* W = (z == 0) ? qW : (z == 1) ? kW : (z == 2) ? vW : oW;
    nbf16* Wt = (z == 3) ? Wto : Wt3 + (size_t)z * WSZ;

    __shared__ float T[64][65];
    const int k0 = blockIdx.x * 64, n0 = blockIdx.y * 64;
    #pragma unroll
    for (int i = 0; i < 16; ++i) {
        const int idx = threadIdx.x + i * 256;
        const int r = idx >> 6, c = idx & 63;
        T[r][c] = ldIn(W, (size_t)(k0 + r) * D_MODEL + n0 + c, flag);
    }
    __syncthreads();
    #pragma unroll
    for (int i = 0; i < 16; ++i) {
        const int idx = threadIdx.x + i * 256;
        const int n = idx >> 6, k = idx & 63;
        Wt[(size_t)(n0 + n) * D_MODEL + k0 + k] = (nbf16)T[k][n];
    }
}

// ---------------------------------------------------------------------------
// 128x128 GEMM staging + K-loop (proven rounds 5-7).
// ---------------------------------------------------------------------------
#define STAGE128(Albuf, Blbuf, Aptr, Bptr, t)                                  \
{                                                                              \
    const int _k0 = (t) * 64;                                                  \
    _Pragma("unroll")                                                          \
    for (int i = 0; i < 4; ++i) {                                              \
        const int row = i * 32 + wid * 8 + (lane >> 3);                        \
        const int ss  = (lane & 7) ^ (row & 7);                                \
        gload_lds16((Aptr) + (size_t)row * D_MODEL + _k0 + ss * 8,             \
                    (nbf16*)(Albuf) + i * 2048 + wid * 512);                   \
        gload_lds16((Bptr) + (size_t)row * D_MODEL + _k0 + ss * 8,             \
                    (nbf16*)(Blbuf) + i * 2048 + wid * 512);                   \
    }                                                                          \
}

#define GEMM128_LOOP(Al, Bl)                                                   \
    const int NT = D_MODEL / 64;                                               \
    for (int t = 0; t < NT; ++t) {                                             \
        const int cur = t & 1;                                                 \
        if (t + 1 < NT)                                                        \
            STAGE128(&Al[cur ^ 1][0][0], &Bl[cur ^ 1][0][0], Am, Bm, t + 1);   \
        _Pragma("unroll")                                                      \
        for (int kk = 0; kk < 2; ++kk) {                                       \
            bf16x8 af[4], bfr[4];                                              \
            _Pragma("unroll")                                                  \
            for (int mi = 0; mi < 4; ++mi) {                                   \
                const int ar = wr * 64 + mi * 16 + l15;                        \
                const int sl = ((kk << 2) + lg) ^ (ar & 7);                    \
                af[mi] = *(const bf16x8*)((const nbf16*)&Al[cur][ar][0] + sl * 8); \
            }                                                                  \
            _Pragma("unroll")                                                  \
            for (int ni = 0; ni < 4; ++ni) {                                   \
                const int br = wc * 64 + ni * 16 + l15;                        \
                const int sl = ((kk << 2) + lg) ^ (br & 7);                    \
                bfr[ni] = *(const bf16x8*)((const nbf16*)&Bl[cur][br][0] + sl * 8); \
            }                                                                  \
            _Pragma("unroll")                                                  \
            for (int mi = 0; mi < 4; ++mi)                                     \
                _Pragma("unroll")                                              \
                for (int ni = 0; ni < 4; ++ni)                                 \
                    acc[mi][ni] = __builtin_amdgcn_mfma_f32_16x16x32_bf16(     \
                        af[mi], bfr[ni], acc[mi][ni], 0, 0, 0);                \
        }                                                                      \
        __syncthreads();                                                       \
    }

// ---------------------------------------------------------------------------
// Fused QKV projection, 128x128 tile (proven rounds 5-7).
// ---------------------------------------------------------------------------
__global__ __launch_bounds__(256, 2) void proj_qkv(
        const nbf16* __restrict__ Xb, const nbf16* __restrict__ Yb,
        const nbf16* __restrict__ Wt3,
        const void* __restrict__ qB, const void* __restrict__ kB,
        const void* __restrict__ vB,
        nbf16* __restrict__ outq, const int* __restrict__ flagp) {
    __shared__ nbf16 Al[2][128][64];
    __shared__ nbf16 Bl[2][128][64];

    const int flag = *flagp;
    const int tid  = threadIdx.x;
    const int wid  = tid >> 6;
    const int lane = tid & 63;
    const int l15  = lane & 15;
    const int lg   = lane >> 4;
    const int wr   = wid >> 1;
    const int wc   = wid & 1;

    const int id = blockIdx.x;
    const int sw = (id & 7) * 96 + (id >> 3);
    const int m0  = (sw & 31) * 128;
    const int ng0 = (sw >> 5) * 128;

    const nbf16* A  = (ng0 < D_MODEL) ? Yb : Xb;
    const nbf16* Bm = Wt3 + (size_t)ng0 * D_MODEL;
    const nbf16* Am = A + (size_t)m0 * D_MODEL;

    f32x4 acc[4][4];
    #pragma unroll
    for (int mi = 0; mi < 4; ++mi)
        #pragma unroll
        for (int ni = 0; ni < 4; ++ni) acc[mi][ni] = (f32x4){0.f, 0.f, 0.f, 0.f};

    STAGE128(&Al[0][0][0], &Bl[0][0][0], Am, Bm, 0);
    __syncthreads();

    GEMM128_LOOP(Al, Bl)

    #pragma unroll
    for (int ni = 0; ni < 4; ++ni) {
        const int n  = ng0 + wc * 64 + ni * 16 + l15;
        const int wh = n >> 10;
        const int nl = n & 1023;
        const void* bp = (wh == 0) ? qB : (wh == 1) ? kB : vB;
        const float bias = ldIn(bp, (size_t)nl, flag);
        nbf16* outp = outq + (size_t)wh * QSZ;
        #pragma unroll
        for (int mi = 0; mi < 4; ++mi) {
            #pragma unroll
            for (int r = 0; r < 4; ++r) {
                const int m = m0 + wr * 64 + mi * 16 + lg * 4 + r;
                const float v = acc[mi][ni][r] + bias;
                const int b = m >> 11, s = m & (SEQ - 1);
                const int h = nl >> 6,  d = nl & (HDK - 1);
                outp[(((size_t)(b * NHEAD + h)) * SEQ + s) * HDK + d] = (nbf16)v;
            }
        }
    }
}

// ---------------------------------------------------------------------------
// O projection, 128x128 tile (proven rounds 5-7).
// ---------------------------------------------------------------------------
__global__ __launch_bounds__(256, 2) void proj_o(
        const nbf16* __restrict__ A, const nbf16* __restrict__ Wt,
        const void* __restrict__ Braw, void* __restrict__ Cout,
        const int* __restrict__ flagp) {
    __shared__ nbf16 Al[2][128][64];
    __shared__ nbf16 Bl[2][128][64];

    const int flag = *flagp;
    const int tid  = threadIdx.x;
    const int wid  = tid >> 6;
    const int lane = tid & 63;
    const int l15  = lane & 15;
    const int lg   = lane >> 4;
    const int wr   = wid >> 1;
    const int wc   = wid & 1;

    const int id = blockIdx.x;
    const int sw = (id & 7) * 32 + (id >> 3);
    const int m0 = (sw >> 3) * 128;
    const int n0 = (sw & 7) * 128;

    const nbf16* Am = A + (size_t)m0 * D_MODEL;
    const nbf16* Bm = Wt + (size_t)n0 * D_MODEL;

    f32x4 acc[4][4];
    #pragma unroll
    for (int mi = 0; mi < 4; ++mi)
        #pragma unroll
        for (int ni = 0; ni < 4; ++ni) acc[mi][ni] = (f32x4){0.f, 0.f, 0.f, 0.f};

    STAGE128(&Al[0][0][0], &Bl[0][0][0], Am, Bm, 0);
    __syncthreads();

    GEMM128_LOOP(Al, Bl)

    #pragma unroll
    for (int ni = 0; ni < 4; ++ni) {
        const int n = n0 + wc * 64 + ni * 16 + l15;
        const float bias = ldIn(Braw, (size_t)n, flag);
        #pragma unroll
        for (int mi = 0; mi < 4; ++mi) {
            #pragma unroll
            for (int r = 0; r < 4; ++r) {
                const int m = m0 + wr * 64 + mi * 16 + lg * 4 + r;
                const float v = acc[mi][ni][r] + bias;
                if (flag) ((bf16*)Cout)[(size_t)m * D_MODEL + n] = __float2bfloat16(v);
                else      ((float*)Cout)[(size_t)m * D_MODEL + n] = v;
            }
        }
    }
}

// ---------------------------------------------------------------------------
// MFMA flash attention v5 = r5 structure (proven fastest: 88.5us) + r7 VALU
// cuts. Evidence ladder: 16q+Kdirect=162 (r3,r6); 32q+Kstaged=88.5 (r5);
// 32q+Kdirect=118 (r7) -> BOTH 32q/wave AND staged K are required.
// - K: global_load_lds double-buffered KL[2][64][64], XOR-swizzled source.
// - V: reg-prefetch + b32 conflict-free VT writes. P: b64 PB writes.
// - Q pre-scaled by 0.125*log2e (bf16 re-round, within tolerance).
// - denominator via ones-MFMA (lands in o[] lane layout; no shfl reductions).
// - T5 setprio, T13 defer-max; round-1 alpha lane-remap rule obeyed.
// ---------------------------------------------------------------------------
__global__ __launch_bounds__(256, 2) void attn_mfma(
        const nbf16* __restrict__ qg, const nbf16* __restrict__ kg,
        const nbf16* __restrict__ vg, nbf16* __restrict__ cg) {
    __shared__ nbf16 KL[2][64][64];   // 16 KB
    __shared__ nbf16 VT[2][64][72];   // 18 KB
    __shared__ nbf16 PB[4][32][72];   // 18 KB -> 52 KB total

    const int tid  = threadIdx.x;
    const int wid  = tid >> 6;
    const int lane = tid & 63;
    const int l15  = lane & 15;
    const int lg   = lane >> 4;

    const int id = blockIdx.x;                // 512 blocks
    const int sw = (id & 7) * 64 + (id >> 3); // bijective XCD swizzle
    const int bh = sw >> 4;                   // 0..31
    const int qt = sw & 15;                   // 0..15

    const nbf16* qb = qg + (size_t)bh * SEQ * HDK;
    const nbf16* kb = kg + (size_t)bh * SEQ * HDK;
    const nbf16* vb = vg + (size_t)bh * SEQ * HDK;

    const float SCf = 0.125f * 1.44269504088896340736f;

    // Q frags (32 q rows), pre-scaled by SCf
    const int qbase = qt * 128 + wid * 32;
    const nbf16* qpA = qb + (size_t)(qbase + l15) * HDK + lg * 8;
    const nbf16* qpB = qpA + 16 * HDK;
    bf16x8 qfA0 = *(const bf16x8*)qpA;
    bf16x8 qfA1 = *(const bf16x8*)(qpA + 32);
    bf16x8 qfB0 = *(const bf16x8*)qpB;
    bf16x8 qfB1 = *(const bf16x8*)(qpB + 32);
    #pragma unroll
    for (int j = 0; j < 8; ++j) {
        qfA0[j] = (nbf16)((float)qfA0[j] * SCf);
        qfA1[j] = (nbf16)((float)qfA1[j] * SCf);
        qfB0[j] = (nbf16)((float)qfB0[j] * SCf);
        qfB1[j] = (nbf16)((float)qfB1[j] * SCf);
    }

    // ones B-frag for the denominator MFMA
    const bf16x8 ones = {(nbf16)1.f, (nbf16)1.f, (nbf16)1.f, (nbf16)1.f,
                         (nbf16)1.f, (nbf16)1.f, (nbf16)1.f, (nbf16)1.f};

    // V staging map: thread covers 8 d x 2 kv, b32 packed writes (r4 proven)
    const int g8 = (tid >> 5) * 8;
    const int p2 = (tid & 31) * 2;

    #define STAGEK(buf, t)                                                     \
    {                                                                          \
        _Pragma("unroll")                                                      \
        for (int i = 0; i < 2; ++i) {                                          \
            const int row = i * 32 + wid * 8 + (lane >> 3);                    \
            const int ss  = (lane & 7) ^ (row & 7);                            \
            gload_lds16(kb + (size_t)((t) * 64 + row) * HDK + ss * 8,          \
                        (nbf16*)&KL[buf][0][0] + i * 2048 + wid * 512);        \
        }                                                                      \
    }

    #define VLOAD(t)                                                           \
        a0 = *(const uint4*)(vb + (size_t)((t) * 64 + p2) * HDK + g8);         \
        a1 = *(const uint4*)(vb + (size_t)((t) * 64 + p2 + 1) * HDK + g8);

    #define VWRITE(buf)                                                        \
    {                                                                          \
        const unsigned short* e0 = (const unsigned short*)&a0;                 \
        const unsigned short* e1 = (const unsigned short*)&a1;                 \
        _Pragma("unroll")                                                      \
        for (int j = 0; j < 8; ++j)                                            \
            *(unsigned int*)&VT[buf][g8 + j][p2] =                             \
                (unsigned int)e0[j] | ((unsigned int)e1[j] << 16);             \
    }

    // T13 defer-max (log2 domain, THR=8); scores arrive pre-scaled.
    // Denominator accumulates via mfma(pf, ones, osum) in the PV section.
    #define SOFTMAX(st, m2, o, osum, pbrow)                                    \
    do {                                                                       \
        float tmx[4];                                                          \
        _Pragma("unroll")                                                      \
        for (int s_ = 0; s_ < 4; ++s_)                                         \
            tmx[s_] = fmaxf(fmaxf(st[s_][0], st[s_][1]),                       \
                            fmaxf(st[s_][2], st[s_][3]));                      \
        float tm = fmaxf(fmaxf(tmx[0], tmx[1]), fmaxf(tmx[2], tmx[3]));        \
        tm = fmaxf(tm, __shfl_xor(tm, 16, 64));                                \
        tm = fmaxf(tm, __shfl_xor(tm, 32, 64));                                \
        const bool nresc = __all(tm - m2 <= 8.0f);                             \
        const float mref = nresc ? m2 : fmaxf(m2, tm);                         \
        _Pragma("unroll")                                                      \
        for (int s_ = 0; s_ < 4; ++s_) {                                       \
            const float p0 = exp2f(st[s_][0] - mref);                          \
            const float p1 = exp2f(st[s_][1] - mref);                          \
            const float p2_ = exp2f(st[s_][2] - mref);                         \
            const float p3 = exp2f(st[s_][3] - mref);                          \
            bf16x4 pk = {(nbf16)p0, (nbf16)p1, (nbf16)p2_, (nbf16)p3};         \
            *(bf16x4*)((pbrow) + s_ * 16 + lg * 4) = pk;                       \
        }                                                                      \
        if (!nresc) {                                                          \
            const float alpha = exp2f(m2 - mref);                              \
            m2 = mref;                                                         \
            float av[4];                                                       \
            _Pragma("unroll")                                                  \
            for (int r = 0; r < 4; ++r) av[r] = __shfl(alpha, lg * 4 + r, 64); \
            _Pragma("unroll")                                                  \
            for (int i = 0; i < 4; ++i)                                        \
                _Pragma("unroll")                                              \
                for (int r = 0; r < 4; ++r) o[i][r] *= av[r];                  \
            _Pragma("unroll")                                                  \
            for (int r = 0; r < 4; ++r) osum[r] *= av[r];                      \
        }                                                                      \
    } while (0)

    float m2A = -3.0e38f, m2B = -3.0e38f;
    f32x4 oA[4], oB[4], osumA, osumB;
    #pragma unroll
    for (int i = 0; i < 4; ++i) { oA[i] = (f32x4){0,0,0,0}; oB[i] = (f32x4){0,0,0,0}; }
    osumA = (f32x4){0, 0, 0, 0};
    osumB = (f32x4){0, 0, 0, 0};

    const int NT = SEQ / 64;   // 32

    {   // prologue: stage K tile 0 (DMA) + V tile 0
        uint4 a0, a1;
        STAGEK(0, 0);
        VLOAD(0);
        VWRITE(0);
    }
    __syncthreads();

    for (int t = 0; t < NT; ++t) {
        const int cur = t & 1;
        uint4 a0, a1;
        if (t + 1 < NT) {
            STAGEK(cur ^ 1, t + 1);   // DMA into other K buffer
            VLOAD(t + 1);             // V regs; written after PV
        }

        // ---- QK^T from KL[cur] ----
        f32x4 stA[4], stB[4];
        __builtin_amdgcn_s_setprio(1);
        #pragma unroll
        for (int sub = 0; sub < 4; ++sub) {
            const int row = sub * 16 + l15;
            const int s0 = lg ^ (row & 7);
            const int s1 = (4 + lg) ^ (row & 7);
            const bf16x8 kf0 = *(const bf16x8*)((const nbf16*)&KL[cur][row][0] + s0 * 8);
            const bf16x8 kf1 = *(const bf16x8*)((const nbf16*)&KL[cur][row][0] + s1 * 8);
            f32x4 a = (f32x4){0,0,0,0};
            a = __builtin_amdgcn_mfma_f32_16x16x32_bf16(kf0, qfA0, a, 0, 0, 0);
            a = __builtin_amdgcn_mfma_f32_16x16x32_bf16(kf1, qfA1, a, 0, 0, 0);
            stA[sub] = a;
            f32x4 b = (f32x4){0,0,0,0};
            b = __builtin_amdgcn_mfma_f32_16x16x32_bf16(kf0, qfB0, b, 0, 0, 0);
            b = __builtin_amdgcn_mfma_f32_16x16x32_bf16(kf1, qfB1, b, 0, 0, 0);
            stB[sub] = b;
        }
        __builtin_amdgcn_s_setprio(0);

        SOFTMAX(stA, m2A, oA, osumA, &PB[wid][l15][0]);
        SOFTMAX(stB, m2B, oB, osumB, &PB[wid][16 + l15][0]);

        // wave-local fence: P ds_writes complete before P ds_reads
        __asm__ volatile("s_waitcnt lgkmcnt(0)" ::: "memory");

        // ---- PV + denominator MFMA ----
        const bf16x8 pfA0 = *(const bf16x8*)&PB[wid][l15][lg * 8];
        const bf16x8 pfA1 = *(const bf16x8*)&PB[wid][l15][lg * 8 + 32];
        const bf16x8 pfB0 = *(const bf16x8*)&PB[wid][16 + l15][lg * 8];
        const bf16x8 pfB1 = *(const bf16x8*)&PB[wid][16 + l15][lg * 8 + 32];
        __builtin_amdgcn_s_setprio(1);
        #pragma unroll
        for (int db = 0; db < 4; ++db) {
            const bf16x8 vf0 = *(const bf16x8*)&VT[cur][db * 16 + l15][lg * 8];
            const bf16x8 vf1 = *(const bf16x8*)&VT[cur][db * 16 + l15][lg * 8 + 32];
            oA[db] = __builtin_amdgcn_mfma_f32_16x16x32_bf16(pfA0, vf0, oA[db], 0, 0, 0);
            oA[db] = __builtin_amdgcn_mfma_f32_16x16x32_bf16(pfA1, vf1, oA[db], 0, 0, 0);
            oB[db] = __builtin_amdgcn_mfma_f32_16x16x32_bf16(pfB0, vf0, oB[db], 0, 0, 0);
            oB[db] = __builtin_amdgcn_mfma_f32_16x16x32_bf16(pfB1, vf1, oB[db], 0, 0, 0);
        }
        osumA = __builtin_amdgcn_mfma_f32_16x16x32_bf16(pfA0, ones, osumA, 0, 0, 0);
        osumA = __builtin_amdgcn_mfma_f32_16x16x32_bf16(pfA1, ones, osumA, 0, 0, 0);
        osumB = __builtin_amdgcn_mfma_f32_16x16x32_bf16(pfB0, ones, osumB, 0, 0, 0);
        osumB = __builtin_amdgcn_mfma_f32_16x16x32_bf16(pfB1, ones, osumB, 0, 0, 0);
        __builtin_amdgcn_s_setprio(0);

        if (t + 1 < NT) VWRITE(cur ^ 1);
        __syncthreads();   // drains K DMA + V/P writes; tile handoff
    }

    // ---- epilogue: osum already in o[] lane layout (no shuffle) ----
    const int b = bh >> 4, h = bh & 15;
    #pragma unroll
    for (int db = 0; db < 4; ++db) {
        #pragma unroll
        for (int r = 0; r < 4; ++r) {
            const int qA = qbase + lg * 4 + r;
            cg[((size_t)(b * SEQ + qA)) * D_MODEL + h * HDK + db * 16 + l15] =
                (nbf16)(oA[db][r] / osumA[r]);
            const int qB_ = qbase + 16 + lg * 4 + r;
            cg[((size_t)(b * SEQ + qB_)) * D_MODEL + h * HDK + db * 16 + l15] =
                (nbf16)(oB[db][r] / osumB[r]);
        }
    }
    #undef STAGEK
    #undef VLOAD
    #undef VWRITE
    #undef SOFTMAX
}

// ---------------------------------------------------------------------------
extern "C" void kernel_launch(void* const* d_in, const int* in_sizes, int n_in,
                              void* d_out, int out_size, void* d_ws, size_t ws_size,
                              hipStream_t stream) {
    const void* X  = d_in[0];
    const void* Y  = d_in[1];
    const void* qW = d_in[2];
    const void* qB = d_in[3];
    const void* kW = d_in[4];
    const void* kB = d_in[5];
    const void* vW = d_in[6];
    const void* vB = d_in[7];
    const void* oW = d_in[8];
    const void* oB = d_in[9];

    nbf16* ws = (nbf16*)d_ws;
    nbf16* qbuf = ws;                  // (B,H,S,dk) bf16; k,v contiguous after
    nbf16* kbuf = qbuf + QSZ;
    nbf16* vbuf = kbuf + QSZ;
    nbf16* cbuf = vbuf + QSZ;          // concat (B,S,D) bf16
    nbf16* Xb   = cbuf + QSZ;
    nbf16* Yb   = Xb + QSZ;
    nbf16* Wt3  = Yb + QSZ;            // [3072][1024] q|k|v
    nbf16* Wto  = Wt3 + 3 * WSZ;
    int*   flag = (int*)(Wto + WSZ);

    detect_dtype<<<1, 256, 0, stream>>>((const unsigned short*)X, flag);

    tobf16_xy<<<(int)(2 * (QSZ / 2048)), 256, 0, stream>>>(X, Y, Xb, Yb, flag);

    wtrans4<<<dim3(16, 16, 4), 256, 0, stream>>>(qW, kW, vW, oW, Wt3, Wto, flag);

    proj_qkv<<<768, 256, 0, stream>>>(Xb, Yb, Wt3, qB, kB, vB, qbuf, flag);

    attn_mfma<<<512, 256, 0, stream>>>(qbuf, kbuf, vbuf, cbuf);

    proj_o<<<256, 256, 0, stream>>>(cbuf, Wto, oB, d_out, flag);
}

// Round 9
// 250.801 us; speedup vs baseline: 1.2984x; 1.0069x over previous
//
#include <hip/hip_runtime.h>
#include <hip/hip_bf16.h>
#include <math.h>

typedef __hip_bfloat16 bf16;
typedef __bf16 nbf16;
typedef __bf16 bf16x8 __attribute__((ext_vector_type(8)));
typedef __bf16 bf16x4 __attribute__((ext_vector_type(4)));
typedef float f32x4 __attribute__((ext_vector_type(4)));

#define D_MODEL 1024
#define NHEAD   16
#define HDK     64
#define BATCH   2
#define SEQ     2048
#define QSZ     ((size_t)BATCH * SEQ * D_MODEL)
#define WSZ     ((size_t)D_MODEL * D_MODEL)

// ---------------------------------------------------------------------------
// Dtype auto-detect (unchanged, proven).
// ---------------------------------------------------------------------------
__global__ void detect_dtype(const unsigned short* __restrict__ x, int* flag) {
    __shared__ int cnt;
    if (threadIdx.x == 0) cnt = 0;
    __syncthreads();
    int local = 0;
    for (int i = threadIdx.x; i < 4096; i += 256) {
        const unsigned short v = x[i];
        const int e = (v >> 7) & 0xFF;
        if (v == 0 || (e >= 96 && e <= 141)) local++;
    }
    atomicAdd(&cnt, local);
    __syncthreads();
    if (threadIdx.x == 0) *flag = (cnt >= 3600) ? 1 : 0;
}

__device__ __forceinline__ float ldIn(const void* p, size_t i, int isbf16) {
    return isbf16 ? __bfloat162float(((const bf16*)p)[i])
                  : ((const float*)p)[i];
}

__device__ __forceinline__ void gload_lds16(const void* g, void* l) {
    __builtin_amdgcn_global_load_lds(
        (const __attribute__((address_space(1))) void*)g,
        (__attribute__((address_space(3))) void*)l, 16, 0, 0);
}

// ---------------------------------------------------------------------------
// prep: fused {X,Y -> bf16 copy} + {4x weight transpose} in ONE launch.
// blocks 0..2047 -> X copy; 2048..4095 -> Y copy; 4096..5119 -> transpose
// (z = (id-4096)>>8 selects weight, tile = (id-4096)&255 -> 64x64 tile).
// ---------------------------------------------------------------------------
__global__ void prep(const void* __restrict__ X, const void* __restrict__ Y,
                     const void* __restrict__ qW, const void* __restrict__ kW,
                     const void* __restrict__ vW, const void* __restrict__ oW,
                     nbf16* __restrict__ Xb, nbf16* __restrict__ Yb,
                     nbf16* __restrict__ Wt3, nbf16* __restrict__ Wto,
                     const int* __restrict__ flagp) {
    const int flag = *flagp;
    const int id = blockIdx.x;
    if (id < 4096) {
        const bool isX = id < 2048;
        const void* in = isX ? X : Y;
        nbf16* out     = isX ? Xb : Yb;
        const size_t i = ((size_t)(isX ? id : id - 2048) * 256 +
                          threadIdx.x) * 8;
        if (flag) {
            *(uint4*)(out + i) = *(const uint4*)((const nbf16*)in + i);
        } else {
            const float4 a = *(const float4*)((const float*)in + i);
            const float4 b = *(const float4*)((const float*)in + i + 4);
            bf16x8 v = {(nbf16)a.x, (nbf16)a.y, (nbf16)a.z, (nbf16)a.w,
                        (nbf16)b.x, (nbf16)b.y, (nbf16)b.z, (nbf16)b.w};
            *(bf16x8*)(out + i) = v;
        }
    } else {
        const int t = id - 4096;
        const int z = t >> 8;
        const int tile = t & 255;
        const void* W = (z == 0) ? qW : (z == 1) ? kW : (z == 2) ? vW : oW;
        nbf16* Wt = (z == 3) ? Wto : Wt3 + (size_t)z * WSZ;

        __shared__ float T[64][65];
        const int k0 = (tile & 15) * 64, n0 = (tile >> 4) * 64;
        #pragma unroll
        for (int i = 0; i < 16; ++i) {
            const int idx = threadIdx.x + i * 256;
            const int r = idx >> 6, c = idx & 63;
            T[r][c] = ldIn(W, (size_t)(k0 + r) * D_MODEL + n0 + c, flag);
        }
        __syncthreads();
        #pragma unroll
        for (int i = 0; i < 16; ++i) {
            const int idx = threadIdx.x + i * 256;
            const int n = idx >> 6, k = idx & 63;
            Wt[(size_t)(n0 + n) * D_MODEL + k0 + k] = (nbf16)T[k][n];
        }
    }
}

// ---------------------------------------------------------------------------
// 128x128 GEMM staging + K-loop (proven rounds 5-8, frozen).
// ---------------------------------------------------------------------------
#define STAGE128(Albuf, Blbuf, Aptr, Bptr, t)                                  \
{                                                                              \
    const int _k0 = (t) * 64;                                                  \
    _Pragma("unroll")                                                          \
    for (int i = 0; i < 4; ++i) {                                              \
        const int row = i * 32 + wid * 8 + (lane >> 3);                        \
        const int ss  = (lane & 7) ^ (row & 7);                                \
        gload_lds16((Aptr) + (size_t)row * D_MODEL + _k0 + ss * 8,             \
                    (nbf16*)(Albuf) + i * 2048 + wid * 512);                   \
        gload_lds16((Bptr) + (size_t)row * D_MODEL + _k0 + ss * 8,             \
                    (nbf16*)(Blbuf) + i * 2048 + wid * 512);                   \
    }                                                                          \
}

#define GEMM128_LOOP(Al, Bl)                                                   \
    const int NT = D_MODEL / 64;                                               \
    for (int t = 0; t < NT; ++t) {                                             \
        const int cur = t & 1;                                                 \
        if (t + 1 < NT)                                                        \
            STAGE128(&Al[cur ^ 1][0][0], &Bl[cur ^ 1][0][0], Am, Bm, t + 1);   \
        _Pragma("unroll")                                                      \
        for (int kk = 0; kk < 2; ++kk) {                                       \
            bf16x8 af[4], bfr[4];                                              \
            _Pragma("unroll")                                                  \
            for (int mi = 0; mi < 4; ++mi) {                                   \
                const int ar = wr * 64 + mi * 16 + l15;                        \
                const int sl = ((kk << 2) + lg) ^ (ar & 7);                    \
                af[mi] = *(const bf16x8*)((const nbf16*)&Al[cur][ar][0] + sl * 8); \
            }                                                                  \
            _Pragma("unroll")                                                  \
            for (int ni = 0; ni < 4; ++ni) {                                   \
                const int br = wc * 64 + ni * 16 + l15;                        \
                const int sl = ((kk << 2) + lg) ^ (br & 7);                    \
                bfr[ni] = *(const bf16x8*)((const nbf16*)&Bl[cur][br][0] + sl * 8); \
            }                                                                  \
            _Pragma("unroll")                                                  \
            for (int mi = 0; mi < 4; ++mi)                                     \
                _Pragma("unroll")                                              \
                for (int ni = 0; ni < 4; ++ni)                                 \
                    acc[mi][ni] = __builtin_amdgcn_mfma_f32_16x16x32_bf16(     \
                        af[mi], bfr[ni], acc[mi][ni], 0, 0, 0);                \
        }                                                                      \
        __syncthreads();                                                       \
    }

// ---------------------------------------------------------------------------
// Fused QKV projection, 128x128 tile (proven rounds 5-8, frozen).
// ---------------------------------------------------------------------------
__global__ __launch_bounds__(256, 2) void proj_qkv(
        const nbf16* __restrict__ Xb, const nbf16* __restrict__ Yb,
        const nbf16* __restrict__ Wt3,
        const void* __restrict__ qB, const void* __restrict__ kB,
        const void* __restrict__ vB,
        nbf16* __restrict__ outq, const int* __restrict__ flagp) {
    __shared__ nbf16 Al[2][128][64];
    __shared__ nbf16 Bl[2][128][64];

    const int flag = *flagp;
    const int tid  = threadIdx.x;
    const int wid  = tid >> 6;
    const int lane = tid & 63;
    const int l15  = lane & 15;
    const int lg   = lane >> 4;
    const int wr   = wid >> 1;
    const int wc   = wid & 1;

    const int id = blockIdx.x;
    const int sw = (id & 7) * 96 + (id >> 3);
    const int m0  = (sw & 31) * 128;
    const int ng0 = (sw >> 5) * 128;

    const nbf16* A  = (ng0 < D_MODEL) ? Yb : Xb;
    const nbf16* Bm = Wt3 + (size_t)ng0 * D_MODEL;
    const nbf16* Am = A + (size_t)m0 * D_MODEL;

    f32x4 acc[4][4];
    #pragma unroll
    for (int mi = 0; mi < 4; ++mi)
        #pragma unroll
        for (int ni = 0; ni < 4; ++ni) acc[mi][ni] = (f32x4){0.f, 0.f, 0.f, 0.f};

    STAGE128(&Al[0][0][0], &Bl[0][0][0], Am, Bm, 0);
    __syncthreads();

    GEMM128_LOOP(Al, Bl)

    #pragma unroll
    for (int ni = 0; ni < 4; ++ni) {
        const int n  = ng0 + wc * 64 + ni * 16 + l15;
        const int wh = n >> 10;
        const int nl = n & 1023;
        const void* bp = (wh == 0) ? qB : (wh == 1) ? kB : vB;
        const float bias = ldIn(bp, (size_t)nl, flag);
        nbf16* outp = outq + (size_t)wh * QSZ;
        #pragma unroll
        for (int mi = 0; mi < 4; ++mi) {
            #pragma unroll
            for (int r = 0; r < 4; ++r) {
                const int m = m0 + wr * 64 + mi * 16 + lg * 4 + r;
                const float v = acc[mi][ni][r] + bias;
                const int b = m >> 11, s = m & (SEQ - 1);
                const int h = nl >> 6,  d = nl & (HDK - 1);
                outp[(((size_t)(b * NHEAD + h)) * SEQ + s) * HDK + d] = (nbf16)v;
            }
        }
    }
}

// ---------------------------------------------------------------------------
// O projection, 128x128 tile (proven rounds 5-8, frozen).
// ---------------------------------------------------------------------------
__global__ __launch_bounds__(256, 2) void proj_o(
        const nbf16* __restrict__ A, const nbf16* __restrict__ Wt,
        const void* __restrict__ Braw, void* __restrict__ Cout,
        const int* __restrict__ flagp) {
    __shared__ nbf16 Al[2][128][64];
    __shared__ nbf16 Bl[2][128][64];

    const int flag = *flagp;
    const int tid  = threadIdx.x;
    const int wid  = tid >> 6;
    const int lane = tid & 63;
    const int l15  = lane & 15;
    const int lg   = lane >> 4;
    const int wr   = wid >> 1;
    const int wc   = wid & 1;

    const int id = blockIdx.x;
    const int sw = (id & 7) * 32 + (id >> 3);
    const int m0 = (sw >> 3) * 128;
    const int n0 = (sw & 7) * 128;

    const nbf16* Am = A + (size_t)m0 * D_MODEL;
    const nbf16* Bm = Wt + (size_t)n0 * D_MODEL;

    f32x4 acc[4][4];
    #pragma unroll
    for (int mi = 0; mi < 4; ++mi)
        #pragma unroll
        for (int ni = 0; ni < 4; ++ni) acc[mi][ni] = (f32x4){0.f, 0.f, 0.f, 0.f};

    STAGE128(&Al[0][0][0], &Bl[0][0][0], Am, Bm, 0);
    __syncthreads();

    GEMM128_LOOP(Al, Bl)

    #pragma unroll
    for (int ni = 0; ni < 4; ++ni) {
        const int n = n0 + wc * 64 + ni * 16 + l15;
        const float bias = ldIn(Braw, (size_t)n, flag);
        #pragma unroll
        for (int mi = 0; mi < 4; ++mi) {
            #pragma unroll
            for (int r = 0; r < 4; ++r) {
                const int m = m0 + wr * 64 + mi * 16 + lg * 4 + r;
                const float v = acc[mi][ni][r] + bias;
                if (flag) ((bf16*)Cout)[(size_t)m * D_MODEL + n] = __float2bfloat16(v);
                else      ((float*)Cout)[(size_t)m * D_MODEL + n] = v;
            }
        }
    }
}

// ---------------------------------------------------------------------------
// MFMA flash attention v6 = r8 structure (85.9us) + XOR-swizzled PB/VT.
// Conflict math (r8 PMC: 5.24M conflict-cyc = ~10% of attn time): unswizzled,
// PB/VT b128 reads put 16 lanes on 4 of 8 16B-slots (half the banks idle);
// PB bf16x4 writes put 16 lanes on one 8B slot. Fix: store element [row][col]
// at [row][col ^ ((row&7)<<3)] (8-elem granule; all accesses are 8B/16B
// chunks within 128B rows -> bijective, alignment-preserving; write and read
// apply the SAME involution -- rule #21). Pads dropped: LDS 52 -> 48KB.
// Everything else identical to r8 (proven).
// ---------------------------------------------------------------------------
__global__ __launch_bounds__(256, 2) void attn_mfma(
        const nbf16* __restrict__ qg, const nbf16* __restrict__ kg,
        const nbf16* __restrict__ vg, nbf16* __restrict__ cg) {
    __shared__ nbf16 KL[2][64][64];   // 16 KB (XOR-swizzled via staging, r5)
    __shared__ nbf16 VT[2][64][64];   // 16 KB (XOR-swizzled, this round)
    __shared__ nbf16 PB[4][32][64];   // 16 KB (XOR-swizzled, this round)

    const int tid  = threadIdx.x;
    const int wid  = tid >> 6;
    const int lane = tid & 63;
    const int l15  = lane & 15;
    const int lg   = lane >> 4;

    const int id = blockIdx.x;                // 512 blocks
    const int sw = (id & 7) * 64 + (id >> 3); // bijective XCD swizzle
    const int bh = sw >> 4;                   // 0..31
    const int qt = sw & 15;                   // 0..15

    const nbf16* qb = qg + (size_t)bh * SEQ * HDK;
    const nbf16* kb = kg + (size_t)bh * SEQ * HDK;
    const nbf16* vb = vg + (size_t)bh * SEQ * HDK;

    const float SCf = 0.125f * 1.44269504088896340736f;

    // Q frags (32 q rows), pre-scaled by SCf (r7/r8 proven)
    const int qbase = qt * 128 + wid * 32;
    const nbf16* qpA = qb + (size_t)(qbase + l15) * HDK + lg * 8;
    const nbf16* qpB = qpA + 16 * HDK;
    bf16x8 qfA0 = *(const bf16x8*)qpA;
    bf16x8 qfA1 = *(const bf16x8*)(qpA + 32);
    bf16x8 qfB0 = *(const bf16x8*)qpB;
    bf16x8 qfB1 = *(const bf16x8*)(qpB + 32);
    #pragma unroll
    for (int j = 0; j < 8; ++j) {
        qfA0[j] = (nbf16)((float)qfA0[j] * SCf);
        qfA1[j] = (nbf16)((float)qfA1[j] * SCf);
        qfB0[j] = (nbf16)((float)qfB0[j] * SCf);
        qfB1[j] = (nbf16)((float)qfB1[j] * SCf);
    }

    // ones B-frag for the denominator MFMA (r7/r8 proven)
    const bf16x8 ones = {(nbf16)1.f, (nbf16)1.f, (nbf16)1.f, (nbf16)1.f,
                         (nbf16)1.f, (nbf16)1.f, (nbf16)1.f, (nbf16)1.f};

    // V staging map: thread covers 8 d x 2 kv, b32 packed writes (r4 proven)
    const int g8 = (tid >> 5) * 8;
    const int p2 = (tid & 31) * 2;

    // swizzled column offsets shared by PB and VT reads (row&7 == l15&7)
    const int swz0 = (lg * 8)      ^ ((l15 & 7) << 3);
    const int swz1 = (lg * 8 + 32) ^ ((l15 & 7) << 3);

    #define STAGEK(buf, t)                                                     \
    {                                                                          \
        _Pragma("unroll")                                                      \
        for (int i = 0; i < 2; ++i) {                                          \
            const int row = i * 32 + wid * 8 + (lane >> 3);                    \
            const int ss  = (lane & 7) ^ (row & 7);                            \
            gload_lds16(kb + (size_t)((t) * 64 + row) * HDK + ss * 8,          \
                        (nbf16*)&KL[buf][0][0] + i * 2048 + wid * 512);        \
        }                                                                      \
    }

    #define VLOAD(t)                                                           \
        a0 = *(const uint4*)(vb + (size_t)((t) * 64 + p2) * HDK + g8);         \
        a1 = *(const uint4*)(vb + (size_t)((t) * 64 + p2 + 1) * HDK + g8);

    // VT[row=d][col=kv], col swizzled by row&7 (= j, since g8 is 8-aligned)
    #define VWRITE(buf)                                                        \
    {                                                                          \
        const unsigned short* e0 = (const unsigned short*)&a0;                 \
        const unsigned short* e1 = (const unsigned short*)&a1;                 \
        _Pragma("unroll")                                                      \
        for (int j = 0; j < 8; ++j)                                            \
            *(unsigned int*)&VT[buf][g8 + j][p2 ^ (j << 3)] =                  \
                (unsigned int)e0[j] | ((unsigned int)e1[j] << 16);             \
    }

    // T13 defer-max (log2 domain, THR=8); scores arrive pre-scaled.
    // P write cols swizzled by l15&7 (row = l15 or 16+l15: same &7).
    #define SOFTMAX(st, m2, o, osum, pbrow)                                    \
    do {                                                                       \
        float tmx[4];                                                          \
        _Pragma("unroll")                                                      \
        for (int s_ = 0; s_ < 4; ++s_)                                         \
            tmx[s_] = fmaxf(fmaxf(st[s_][0], st[s_][1]),                       \
                            fmaxf(st[s_][2], st[s_][3]));                      \
        float tm = fmaxf(fmaxf(tmx[0], tmx[1]), fmaxf(tmx[2], tmx[3]));        \
        tm = fmaxf(tm, __shfl_xor(tm, 16, 64));                                \
        tm = fmaxf(tm, __shfl_xor(tm, 32, 64));                                \
        const bool nresc = __all(tm - m2 <= 8.0f);                             \
        const float mref = nresc ? m2 : fmaxf(m2, tm);                         \
        _Pragma("unroll")                                                      \
        for (int s_ = 0; s_ < 4; ++s_) {                                       \
            const float p0 = exp2f(st[s_][0] - mref);                          \
            const float p1 = exp2f(st[s_][1] - mref);                          \
            const float p2_ = exp2f(st[s_][2] - mref);                         \
            const float p3 = exp2f(st[s_][3] - mref);                          \
            bf16x4 pk = {(nbf16)p0, (nbf16)p1, (nbf16)p2_, (nbf16)p3};         \
            *(bf16x4*)((pbrow) + ((s_ * 16 + lg * 4) ^ ((l15 & 7) << 3))) = pk;\
        }                                                                      \
        if (!nresc) {                                                          \
            const float alpha = exp2f(m2 - mref);                              \
            m2 = mref;                                                         \
            float av[4];                                                       \
            _Pragma("unroll")                                                  \
            for (int r = 0; r < 4; ++r) av[r] = __shfl(alpha, lg * 4 + r, 64); \
            _Pragma("unroll")                                                  \
            for (int i = 0; i < 4; ++i)                                        \
                _Pragma("unroll")                                              \
                for (int r = 0; r < 4; ++r) o[i][r] *= av[r];                  \
            _Pragma("unroll")                                                  \
            for (int r = 0; r < 4; ++r) osum[r] *= av[r];                      \
        }                                                                      \
    } while (0)

    float m2A = -3.0e38f, m2B = -3.0e38f;
    f32x4 oA[4], oB[4], osumA, osumB;
    #pragma unroll
    for (int i = 0; i < 4; ++i) { oA[i] = (f32x4){0,0,0,0}; oB[i] = (f32x4){0,0,0,0}; }
    osumA = (f32x4){0, 0, 0, 0};
    osumB = (f32x4){0, 0, 0, 0};

    const int NT = SEQ / 64;   // 32

    {   // prologue: stage K tile 0 (DMA) + V tile 0
        uint4 a0, a1;
        STAGEK(0, 0);
        VLOAD(0);
        VWRITE(0);
    }
    __syncthreads();

    for (int t = 0; t < NT; ++t) {
        const int cur = t & 1;
        uint4 a0, a1;
        if (t + 1 < NT) {
            STAGEK(cur ^ 1, t + 1);   // DMA into other K buffer
            VLOAD(t + 1);             // V regs; written after PV
        }

        // ---- QK^T from KL[cur] ----
        f32x4 stA[4], stB[4];
        __builtin_amdgcn_s_setprio(1);
        #pragma unroll
        for (int sub = 0; sub < 4; ++sub) {
            const int row = sub * 16 + l15;
            const int s0 = lg ^ (row & 7);
            const int s1 = (4 + lg) ^ (row & 7);
            const bf16x8 kf0 = *(const bf16x8*)((const nbf16*)&KL[cur][row][0] + s0 * 8);
            const bf16x8 kf1 = *(const bf16x8*)((const nbf16*)&KL[cur][row][0] + s1 * 8);
            f32x4 a = (f32x4){0,0,0,0};
            a = __builtin_amdgcn_mfma_f32_16x16x32_bf16(kf0, qfA0, a, 0, 0, 0);
            a = __builtin_amdgcn_mfma_f32_16x16x32_bf16(kf1, qfA1, a, 0, 0, 0);
            stA[sub] = a;
            f32x4 b = (f32x4){0,0,0,0};
            b = __builtin_amdgcn_mfma_f32_16x16x32_bf16(kf0, qfB0, b, 0, 0, 0);
            b = __builtin_amdgcn_mfma_f32_16x16x32_bf16(kf1, qfB1, b, 0, 0, 0);
            stB[sub] = b;
        }
        __builtin_amdgcn_s_setprio(0);

        SOFTMAX(stA, m2A, oA, osumA, &PB[wid][l15][0]);
        SOFTMAX(stB, m2B, oB, osumB, &PB[wid][16 + l15][0]);

        // wave-local fence: P ds_writes complete before P ds_reads
        __asm__ volatile("s_waitcnt lgkmcnt(0)" ::: "memory");

        // ---- PV + denominator MFMA (swizzled P/V reads) ----
        const nbf16* pbA = &PB[wid][l15][0];
        const nbf16* pbB = &PB[wid][16 + l15][0];
        const bf16x8 pfA0 = *(const bf16x8*)(pbA + swz0);
        const bf16x8 pfA1 = *(const bf16x8*)(pbA + swz1);
        const bf16x8 pfB0 = *(const bf16x8*)(pbB + swz0);
        const bf16x8 pfB1 = *(const bf16x8*)(pbB + swz1);
        __builtin_amdgcn_s_setprio(1);
        #pragma unroll
        for (int db = 0; db < 4; ++db) {
            const nbf16* vr = &VT[cur][db * 16 + l15][0];
            const bf16x8 vf0 = *(const bf16x8*)(vr + swz0);
            const bf16x8 vf1 = *(const bf16x8*)(vr + swz1);
            oA[db] = __builtin_amdgcn_mfma_f32_16x16x32_bf16(pfA0, vf0, oA[db], 0, 0, 0);
            oA[db] = __builtin_amdgcn_mfma_f32_16x16x32_bf16(pfA1, vf1, oA[db], 0, 0, 0);
            oB[db] = __builtin_amdgcn_mfma_f32_16x16x32_bf16(pfB0, vf0, oB[db], 0, 0, 0);
            oB[db] = __builtin_amdgcn_mfma_f32_16x16x32_bf16(pfB1, vf1, oB[db], 0, 0, 0);
        }
        osumA = __builtin_amdgcn_mfma_f32_16x16x32_bf16(pfA0, ones, osumA, 0, 0, 0);
        osumA = __builtin_amdgcn_mfma_f32_16x16x32_bf16(pfA1, ones, osumA, 0, 0, 0);
        osumB = __builtin_amdgcn_mfma_f32_16x16x32_bf16(pfB0, ones, osumB, 0, 0, 0);
        osumB = __builtin_amdgcn_mfma_f32_16x16x32_bf16(pfB1, ones, osumB, 0, 0, 0);
        __builtin_amdgcn_s_setprio(0);

        if (t + 1 < NT) VWRITE(cur ^ 1);
        __syncthreads();   // drains K DMA + V/P writes; tile handoff
    }

    // ---- epilogue: osum already in o[] lane layout (no shuffle) ----
    const int b = bh >> 4, h = bh & 15;
    #pragma unroll
    for (int db = 0; db < 4; ++db) {
        #pragma unroll
        for (int r = 0; r < 4; ++r) {
            const int qA = qbase + lg * 4 + r;
            cg[((size_t)(b * SEQ + qA)) * D_MODEL + h * HDK + db * 16 + l15] =
                (nbf16)(oA[db][r] / osumA[r]);
            const int qB_ = qbase + 16 + lg * 4 + r;
            cg[((size_t)(b * SEQ + qB_)) * D_MODEL + h * HDK + db * 16 + l15] =
                (nbf16)(oB[db][r] / osumB[r]);
        }
    }
    #undef STAGEK
    #undef VLOAD
    #undef VWRITE
    #undef SOFTMAX
}

// ---------------------------------------------------------------------------
extern "C" void kernel_launch(void* const* d_in, const int* in_sizes, int n_in,
                              void* d_out, int out_size, void* d_ws, size_t ws_size,
                              hipStream_t stream) {
    const void* X  = d_in[0];
    const void* Y  = d_in[1];
    const void* qW = d_in[2];
    const void* qB = d_in[3];
    const void* kW = d_in[4];
    const void* kB = d_in[5];
    const void* vW = d_in[6];
    const void* vB = d_in[7];
    const void* oW = d_in[8];
    const void* oB = d_in[9];

    nbf16* ws = (nbf16*)d_ws;
    nbf16* qbuf = ws;                  // (B,H,S,dk) bf16; k,v contiguous after
    nbf16* kbuf = qbuf + QSZ;
    nbf16* vbuf = kbuf + QSZ;
    nbf16* cbuf = vbuf + QSZ;          // concat (B,S,D) bf16
    nbf16* Xb   = cbuf + QSZ;
    nbf16* Yb   = Xb + QSZ;
    nbf16* Wt3  = Yb + QSZ;            // [3072][1024] q|k|v
    nbf16* Wto  = Wt3 + 3 * WSZ;
    int*   flag = (int*)(Wto + WSZ);

    detect_dtype<<<1, 256, 0, stream>>>((const unsigned short*)X, flag);

    prep<<<5120, 256, 0, stream>>>(X, Y, qW, kW, vW, oW, Xb, Yb, Wt3, Wto, flag);

    proj_qkv<<<768, 256, 0, stream>>>(Xb, Yb, Wt3, qB, kB, vB, qbuf, flag);

    attn_mfma<<<512, 256, 0, stream>>>(qbuf, kbuf, vbuf, cbuf);

    proj_o<<<256, 256, 0, stream>>>(cbuf, Wto, oB, d_out, flag);
}

// Round 11
// 250.551 us; speedup vs baseline: 1.2997x; 1.0010x over previous
//
#include <hip/hip_runtime.h>
#include <hip/hip_bf16.h>
#include <math.h>

typedef __hip_bfloat16 bf16;
typedef __bf16 nbf16;
typedef __bf16 bf16x8 __attribute__((ext_vector_type(8)));
typedef __bf16 bf16x4 __attribute__((ext_vector_type(4)));
typedef float f32x4 __attribute__((ext_vector_type(4)));

#define D_MODEL 1024
#define NHEAD   16
#define HDK     64
#define BATCH   2
#define SEQ     2048
#define QSZ     ((size_t)BATCH * SEQ * D_MODEL)
#define WSZ     ((size_t)D_MODEL * D_MODEL)

// ---------------------------------------------------------------------------
// Dtype auto-detect (unchanged, proven).
// ---------------------------------------------------------------------------
__global__ void detect_dtype(const unsigned short* __restrict__ x, int* flag) {
    __shared__ int cnt;
    if (threadIdx.x == 0) cnt = 0;
    __syncthreads();
    int local = 0;
    for (int i = threadIdx.x; i < 4096; i += 256) {
        const unsigned short v = x[i];
        const int e = (v >> 7) & 0xFF;
        if (v == 0 || (e >= 96 && e <= 141)) local++;
    }
    atomicAdd(&cnt, local);
    __syncthreads();
    if (threadIdx.x == 0) *flag = (cnt >= 3600) ? 1 : 0;
}

__device__ __forceinline__ float ldIn(const void* p, size_t i, int isbf16) {
    return isbf16 ? __bfloat162float(((const bf16*)p)[i])
                  : ((const float*)p)[i];
}

__device__ __forceinline__ void gload_lds16(const void* g, void* l) {
    __builtin_amdgcn_global_load_lds(
        (const __attribute__((address_space(1))) void*)g,
        (__attribute__((address_space(3))) void*)l, 16, 0, 0);
}

// ---------------------------------------------------------------------------
// prep: fused {X,Y -> bf16} + {4x weight transpose} (proven rounds 8-9).
// ---------------------------------------------------------------------------
__global__ void prep(const void* __restrict__ X, const void* __restrict__ Y,
                     const void* __restrict__ qW, const void* __restrict__ kW,
                     const void* __restrict__ vW, const void* __restrict__ oW,
                     nbf16* __restrict__ Xb, nbf16* __restrict__ Yb,
                     nbf16* __restrict__ Wt3, nbf16* __restrict__ Wto,
                     const int* __restrict__ flagp) {
    const int flag = *flagp;
    const int id = blockIdx.x;
    if (id < 4096) {
        const bool isX = id < 2048;
        const void* in = isX ? X : Y;
        nbf16* out     = isX ? Xb : Yb;
        const size_t i = ((size_t)(isX ? id : id - 2048) * 256 +
                          threadIdx.x) * 8;
        if (flag) {
            *(uint4*)(out + i) = *(const uint4*)((const nbf16*)in + i);
        } else {
            const float4 a = *(const float4*)((const float*)in + i);
            const float4 b = *(const float4*)((const float*)in + i + 4);
            bf16x8 v = {(nbf16)a.x, (nbf16)a.y, (nbf16)a.z, (nbf16)a.w,
                        (nbf16)b.x, (nbf16)b.y, (nbf16)b.z, (nbf16)b.w};
            *(bf16x8*)(out + i) = v;
        }
    } else {
        const int t = id - 4096;
        const int z = t >> 8;
        const int tile = t & 255;
        const void* W = (z == 0) ? qW : (z == 1) ? kW : (z == 2) ? vW : oW;
        nbf16* Wt = (z == 3) ? Wto : Wt3 + (size_t)z * WSZ;

        __shared__ float T[64][65];
        const int k0 = (tile & 15) * 64, n0 = (tile >> 4) * 64;
        #pragma unroll
        for (int i = 0; i < 16; ++i) {
            const int idx = threadIdx.x + i * 256;
            const int r = idx >> 6, c = idx & 63;
            T[r][c] = ldIn(W, (size_t)(k0 + r) * D_MODEL + n0 + c, flag);
        }
        __syncthreads();
        #pragma unroll
        for (int i = 0; i < 16; ++i) {
            const int idx = threadIdx.x + i * 256;
            const int n = idx >> 6, k = idx & 63;
            Wt[(size_t)(n0 + n) * D_MODEL + k0 + k] = (nbf16)T[k][n];
        }
    }
}

// ---------------------------------------------------------------------------
// Single-buffer staging for the m97-style proj_qkv (32 KB LDS, 3 blk/CU).
// ---------------------------------------------------------------------------
#define STAGE1(Albuf, Blbuf, Aptr, Bptr, t)                                    \
{                                                                              \
    const int _k0 = (t) * 64;                                                  \
    _Pragma("unroll")                                                          \
    for (int i = 0; i < 4; ++i) {                                              \
        const int row = i * 32 + wid * 8 + (lane >> 3);                        \
        const int ss  = (lane & 7) ^ (row & 7);                                \
        gload_lds16((Aptr) + (size_t)row * D_MODEL + _k0 + ss * 8,             \
                    (nbf16*)(Albuf) + i * 2048 + wid * 512);                   \
        gload_lds16((Bptr) + (size_t)row * D_MODEL + _k0 + ss * 8,             \
                    (nbf16*)(Blbuf) + i * 2048 + wid * 512);                   \
    }                                                                          \
}

// ---------------------------------------------------------------------------
// Fused QKV projection, m97 structure: 128x128 tile, BK=64, SINGLE-buffered
// LDS (32 KB), 2 barriers per K-step, 3 blocks/CU, grid 768 = single pass.
// ---------------------------------------------------------------------------
__global__ __launch_bounds__(256, 3) void proj_qkv(
        const nbf16* __restrict__ Xb, const nbf16* __restrict__ Yb,
        const nbf16* __restrict__ Wt3,
        const void* __restrict__ qB, const void* __restrict__ kB,
        const void* __restrict__ vB,
        nbf16* __restrict__ outq, const int* __restrict__ flagp) {
    __shared__ nbf16 Al[128][64];   // 16 KB
    __shared__ nbf16 Bl[128][64];   // 16 KB

    const int flag = *flagp;
    const int tid  = threadIdx.x;
    const int wid  = tid >> 6;
    const int lane = tid & 63;
    const int l15  = lane & 15;
    const int lg   = lane >> 4;
    const int wr   = wid >> 1;
    const int wc   = wid & 1;

    const int id = blockIdx.x;
    const int sw = (id & 7) * 96 + (id >> 3);
    const int m0  = (sw & 31) * 128;
    const int ng0 = (sw >> 5) * 128;

    const nbf16* A  = (ng0 < D_MODEL) ? Yb : Xb;
    const nbf16* Bm = Wt3 + (size_t)ng0 * D_MODEL;
    const nbf16* Am = A + (size_t)m0 * D_MODEL;

    f32x4 acc[4][4];
    #pragma unroll
    for (int mi = 0; mi < 4; ++mi)
        #pragma unroll
        for (int ni = 0; ni < 4; ++ni) acc[mi][ni] = (f32x4){0.f, 0.f, 0.f, 0.f};

    const int NT = D_MODEL / 64;   // 16
    for (int t = 0; t < NT; ++t) {
        STAGE1(&Al[0][0], &Bl[0][0], Am, Bm, t);
        __syncthreads();   // drains staging DMA (vmcnt(0) before barrier)
        #pragma unroll
        for (int kk = 0; kk < 2; ++kk) {
            bf16x8 af[4], bfr[4];
            #pragma unroll
            for (int mi = 0; mi < 4; ++mi) {
                const int ar = wr * 64 + mi * 16 + l15;
                const int sl = ((kk << 2) + lg) ^ (ar & 7);
                af[mi] = *(const bf16x8*)((const nbf16*)&Al[ar][0] + sl * 8);
            }
            #pragma unroll
            for (int ni = 0; ni < 4; ++ni) {
                const int br = wc * 64 + ni * 16 + l15;
                const int sl = ((kk << 2) + lg) ^ (br & 7);
                bfr[ni] = *(const bf16x8*)((const nbf16*)&Bl[br][0] + sl * 8);
            }
            #pragma unroll
            for (int mi = 0; mi < 4; ++mi)
                #pragma unroll
                for (int ni = 0; ni < 4; ++ni)
                    acc[mi][ni] = __builtin_amdgcn_mfma_f32_16x16x32_bf16(
                        af[mi], bfr[ni], acc[mi][ni], 0, 0, 0);
        }
        __syncthreads();   // all reads done before next stage overwrites
    }

    #pragma unroll
    for (int ni = 0; ni < 4; ++ni) {
        const int n  = ng0 + wc * 64 + ni * 16 + l15;
        const int wh = n >> 10;
        const int nl = n & 1023;
        const void* bp = (wh == 0) ? qB : (wh == 1) ? kB : vB;
        const float bias = ldIn(bp, (size_t)nl, flag);
        nbf16* outp = outq + (size_t)wh * QSZ;
        #pragma unroll
        for (int mi = 0; mi < 4; ++mi) {
            #pragma unroll
            for (int r = 0; r < 4; ++r) {
                const int m = m0 + wr * 64 + mi * 16 + lg * 4 + r;
                const float v = acc[mi][ni][r] + bias;
                const int b = m >> 11, s = m & (SEQ - 1);
                const int h = nl >> 6,  d = nl & (HDK - 1);
                outp[(((size_t)(b * NHEAD + h)) * SEQ + s) * HDK + d] = (nbf16)v;
            }
        }
    }
}

// ---------------------------------------------------------------------------
// O projection, 128x128 dbuf (proven rounds 5-9, frozen).
// ---------------------------------------------------------------------------
#define STAGE128(Albuf, Blbuf, Aptr, Bptr, t)                                  \
{                                                                              \
    const int _k0 = (t) * 64;                                                  \
    _Pragma("unroll")                                                          \
    for (int i = 0; i < 4; ++i) {                                              \
        const int row = i * 32 + wid * 8 + (lane >> 3);                        \
        const int ss  = (lane & 7) ^ (row & 7);                                \
        gload_lds16((Aptr) + (size_t)row * D_MODEL + _k0 + ss * 8,             \
                    (nbf16*)(Albuf) + i * 2048 + wid * 512);                   \
        gload_lds16((Bptr) + (size_t)row * D_MODEL + _k0 + ss * 8,             \
                    (nbf16*)(Blbuf) + i * 2048 + wid * 512);                   \
    }                                                                          \
}

__global__ __launch_bounds__(256, 2) void proj_o(
        const nbf16* __restrict__ A, const nbf16* __restrict__ Wt,
        const void* __restrict__ Braw, void* __restrict__ Cout,
        const int* __restrict__ flagp) {
    __shared__ nbf16 Al[2][128][64];
    __shared__ nbf16 Bl[2][128][64];

    const int flag = *flagp;
    const int tid  = threadIdx.x;
    const int wid  = tid >> 6;
    const int lane = tid & 63;
    const int l15  = lane & 15;
    const int lg   = lane >> 4;
    const int wr   = wid >> 1;
    const int wc   = wid & 1;

    const int id = blockIdx.x;
    const int sw = (id & 7) * 32 + (id >> 3);
    const int m0 = (sw >> 3) * 128;
    const int n0 = (sw & 7) * 128;

    const nbf16* Am = A + (size_t)m0 * D_MODEL;
    const nbf16* Bm = Wt + (size_t)n0 * D_MODEL;

    f32x4 acc[4][4];
    #pragma unroll
    for (int mi = 0; mi < 4; ++mi)
        #pragma unroll
        for (int ni = 0; ni < 4; ++ni) acc[mi][ni] = (f32x4){0.f, 0.f, 0.f, 0.f};

    STAGE128(&Al[0][0][0], &Bl[0][0][0], Am, Bm, 0);
    __syncthreads();

    const int NT = D_MODEL / 64;
    for (int t = 0; t < NT; ++t) {
        const int cur = t & 1;
        if (t + 1 < NT)
            STAGE128(&Al[cur ^ 1][0][0], &Bl[cur ^ 1][0][0], Am, Bm, t + 1);
        #pragma unroll
        for (int kk = 0; kk < 2; ++kk) {
            bf16x8 af[4], bfr[4];
            #pragma unroll
            for (int mi = 0; mi < 4; ++mi) {
                const int ar = wr * 64 + mi * 16 + l15;
                const int sl = ((kk << 2) + lg) ^ (ar & 7);
                af[mi] = *(const bf16x8*)((const nbf16*)&Al[cur][ar][0] + sl * 8);
            }
            #pragma unroll
            for (int ni = 0; ni < 4; ++ni) {
                const int br = wc * 64 + ni * 16 + l15;
                const int sl = ((kk << 2) + lg) ^ (br & 7);
                bfr[ni] = *(const bf16x8*)((const nbf16*)&Bl[cur][br][0] + sl * 8);
            }
            #pragma unroll
            for (int mi = 0; mi < 4; ++mi)
                #pragma unroll
                for (int ni = 0; ni < 4; ++ni)
                    acc[mi][ni] = __builtin_amdgcn_mfma_f32_16x16x32_bf16(
                        af[mi], bfr[ni], acc[mi][ni], 0, 0, 0);
        }
        __syncthreads();
    }

    #pragma unroll
    for (int ni = 0; ni < 4; ++ni) {
        const int n = n0 + wc * 64 + ni * 16 + l15;
        const float bias = ldIn(Braw, (size_t)n, flag);
        #pragma unroll
        for (int mi = 0; mi < 4; ++mi) {
            #pragma unroll
            for (int r = 0; r < 4; ++r) {
                const int m = m0 + wr * 64 + mi * 16 + lg * 4 + r;
                const float v = acc[mi][ni][r] + bias;
                if (flag) ((bf16*)Cout)[(size_t)m * D_MODEL + n] = __float2bfloat16(v);
                else      ((float*)Cout)[(size_t)m * D_MODEL + n] = v;
            }
        }
    }
}

// ---------------------------------------------------------------------------
// MFMA flash attention, template<SPLIT>.
// SPLIT=false: r9-proven kernel byte-for-byte logic (grid 512, 250.8us total).
// SPLIT=true : kv-split x2 (grid 1024, ~3 blk/CU) writing unnormalized f32
// partials + per-q {m, osum}; attn_combine merges exactly. Chosen at launch
// ONLY if ws_size fits the 33MB partial buffers (r10 lesson: never assume).
// ---------------------------------------------------------------------------
template<bool SPLIT>
__global__ __launch_bounds__(256, SPLIT ? 3 : 2) void attn_mfma(
        const nbf16* __restrict__ qg, const nbf16* __restrict__ kg,
        const nbf16* __restrict__ vg, nbf16* __restrict__ cg,
        float* __restrict__ part_o, float2* __restrict__ part_ms) {
    __shared__ nbf16 KL[2][64][64];   // 16 KB
    __shared__ nbf16 VT[2][64][64];   // 16 KB (XOR-swizzled)
    __shared__ nbf16 PB[4][32][64];   // 16 KB (XOR-swizzled)

    const int tid  = threadIdx.x;
    const int wid  = tid >> 6;
    const int lane = tid & 63;
    const int l15  = lane & 15;
    const int lg   = lane >> 4;

    const int id = blockIdx.x;
    const int sw = SPLIT ? ((id & 7) * 128 + (id >> 3))
                         : ((id & 7) * 64 + (id >> 3));
    const int bh   = SPLIT ? (sw >> 5) : (sw >> 4);
    const int qt   = SPLIT ? ((sw & 31) >> 1) : (sw & 15);
    const int half = SPLIT ? (sw & 1) : 0;

    const nbf16* qb = qg + (size_t)bh * SEQ * HDK;
    const nbf16* kb = kg + (size_t)bh * SEQ * HDK +
                      (size_t)half * (SEQ / 2) * HDK;
    const nbf16* vb = vg + (size_t)bh * SEQ * HDK +
                      (size_t)half * (SEQ / 2) * HDK;

    const float SCf = 0.125f * 1.44269504088896340736f;

    const int qbase = qt * 128 + wid * 32;
    const nbf16* qpA = qb + (size_t)(qbase + l15) * HDK + lg * 8;
    const nbf16* qpB = qpA + 16 * HDK;
    bf16x8 qfA0 = *(const bf16x8*)qpA;
    bf16x8 qfA1 = *(const bf16x8*)(qpA + 32);
    bf16x8 qfB0 = *(const bf16x8*)qpB;
    bf16x8 qfB1 = *(const bf16x8*)(qpB + 32);
    #pragma unroll
    for (int j = 0; j < 8; ++j) {
        qfA0[j] = (nbf16)((float)qfA0[j] * SCf);
        qfA1[j] = (nbf16)((float)qfA1[j] * SCf);
        qfB0[j] = (nbf16)((float)qfB0[j] * SCf);
        qfB1[j] = (nbf16)((float)qfB1[j] * SCf);
    }

    const bf16x8 ones = {(nbf16)1.f, (nbf16)1.f, (nbf16)1.f, (nbf16)1.f,
                         (nbf16)1.f, (nbf16)1.f, (nbf16)1.f, (nbf16)1.f};

    const int g8 = (tid >> 5) * 8;
    const int p2 = (tid & 31) * 2;

    const int swz0 = (lg * 8)      ^ ((l15 & 7) << 3);
    const int swz1 = (lg * 8 + 32) ^ ((l15 & 7) << 3);

    #define STAGEK(buf, t)                                                     \
    {                                                                          \
        _Pragma("unroll")                                                      \
        for (int i = 0; i < 2; ++i) {                                          \
            const int row = i * 32 + wid * 8 + (lane >> 3);                    \
            const int ss  = (lane & 7) ^ (row & 7);                            \
            gload_lds16(kb + (size_t)((t) * 64 + row) * HDK + ss * 8,          \
                        (nbf16*)&KL[buf][0][0] + i * 2048 + wid * 512);        \
        }                                                                      \
    }

    #define VLOAD(t)                                                           \
        a0 = *(const uint4*)(vb + (size_t)((t) * 64 + p2) * HDK + g8);         \
        a1 = *(const uint4*)(vb + (size_t)((t) * 64 + p2 + 1) * HDK + g8);

    #define VWRITE(buf)                                                        \
    {                                                                          \
        const unsigned short* e0 = (const unsigned short*)&a0;                 \
        const unsigned short* e1 = (const unsigned short*)&a1;                 \
        _Pragma("unroll")                                                      \
        for (int j = 0; j < 8; ++j)                                            \
            *(unsigned int*)&VT[buf][g8 + j][p2 ^ (j << 3)] =                  \
                (unsigned int)e0[j] | ((unsigned int)e1[j] << 16);             \
    }

    #define SOFTMAX(st, m2, o, osum, pbrow)                                    \
    do {                                                                       \
        float tmx[4];                                                          \
        _Pragma("unroll")                                                      \
        for (int s_ = 0; s_ < 4; ++s_)                                         \
            tmx[s_] = fmaxf(fmaxf(st[s_][0], st[s_][1]),                       \
                            fmaxf(st[s_][2], st[s_][3]));                      \
        float tm = fmaxf(fmaxf(tmx[0], tmx[1]), fmaxf(tmx[2], tmx[3]));        \
        tm = fmaxf(tm, __shfl_xor(tm, 16, 64));                                \
        tm = fmaxf(tm, __shfl_xor(tm, 32, 64));                                \
        const bool nresc = __all(tm - m2 <= 8.0f);                             \
        const float mref = nresc ? m2 : fmaxf(m2, tm);                         \
        _Pragma("unroll")                                                      \
        for (int s_ = 0; s_ < 4; ++s_) {                                       \
            const float p0 = exp2f(st[s_][0] - mref);                          \
            const float p1 = exp2f(st[s_][1] - mref);                          \
            const float p2_ = exp2f(st[s_][2] - mref);                         \
            const float p3 = exp2f(st[s_][3] - mref);                          \
            bf16x4 pk = {(nbf16)p0, (nbf16)p1, (nbf16)p2_, (nbf16)p3};         \
            *(bf16x4*)((pbrow) + ((s_ * 16 + lg * 4) ^ ((l15 & 7) << 3))) = pk;\
        }                                                                      \
        if (!nresc) {                                                          \
            const float alpha = exp2f(m2 - mref);                              \
            m2 = mref;                                                         \
            float av[4];                                                       \
            _Pragma("unroll")                                                  \
            for (int r = 0; r < 4; ++r) av[r] = __shfl(alpha, lg * 4 + r, 64); \
            _Pragma("unroll")                                                  \
            for (int i = 0; i < 4; ++i)                                        \
                _Pragma("unroll")                                              \
                for (int r = 0; r < 4; ++r) o[i][r] *= av[r];                  \
            _Pragma("unroll")                                                  \
            for (int r = 0; r < 4; ++r) osum[r] *= av[r];                      \
        }                                                                      \
    } while (0)

    float m2A = -3.0e38f, m2B = -3.0e38f;
    f32x4 oA[4], oB[4], osumA, osumB;
    #pragma unroll
    for (int i = 0; i < 4; ++i) { oA[i] = (f32x4){0,0,0,0}; oB[i] = (f32x4){0,0,0,0}; }
    osumA = (f32x4){0, 0, 0, 0};
    osumB = (f32x4){0, 0, 0, 0};

    const int NT = SPLIT ? (SEQ / 2) / 64 : SEQ / 64;

    {   // prologue: stage K tile 0 (DMA) + V tile 0
        uint4 a0, a1;
        STAGEK(0, 0);
        VLOAD(0);
        VWRITE(0);
    }
    __syncthreads();

    for (int t = 0; t < NT; ++t) {
        const int cur = t & 1;
        uint4 a0, a1;
        if (t + 1 < NT) {
            STAGEK(cur ^ 1, t + 1);
            VLOAD(t + 1);
        }

        // ---- QK^T from KL[cur] ----
        f32x4 stA[4], stB[4];
        __builtin_amdgcn_s_setprio(1);
        #pragma unroll
        for (int sub = 0; sub < 4; ++sub) {
            const int row = sub * 16 + l15;
            const int s0 = lg ^ (row & 7);
            const int s1 = (4 + lg) ^ (row & 7);
            const bf16x8 kf0 = *(const bf16x8*)((const nbf16*)&KL[cur][row][0] + s0 * 8);
            const bf16x8 kf1 = *(const bf16x8*)((const nbf16*)&KL[cur][row][0] + s1 * 8);
            f32x4 a = (f32x4){0,0,0,0};
            a = __builtin_amdgcn_mfma_f32_16x16x32_bf16(kf0, qfA0, a, 0, 0, 0);
            a = __builtin_amdgcn_mfma_f32_16x16x32_bf16(kf1, qfA1, a, 0, 0, 0);
            stA[sub] = a;
            f32x4 b = (f32x4){0,0,0,0};
            b = __builtin_amdgcn_mfma_f32_16x16x32_bf16(kf0, qfB0, b, 0, 0, 0);
            b = __builtin_amdgcn_mfma_f32_16x16x32_bf16(kf1, qfB1, b, 0, 0, 0);
            stB[sub] = b;
        }
        __builtin_amdgcn_s_setprio(0);

        SOFTMAX(stA, m2A, oA, osumA, &PB[wid][l15][0]);
        SOFTMAX(stB, m2B, oB, osumB, &PB[wid][16 + l15][0]);

        __asm__ volatile("s_waitcnt lgkmcnt(0)" ::: "memory");

        // ---- PV + denominator MFMA (swizzled P/V reads) ----
        const nbf16* pbA = &PB[wid][l15][0];
        const nbf16* pbB = &PB[wid][16 + l15][0];
        const bf16x8 pfA0 = *(const bf16x8*)(pbA + swz0);
        const bf16x8 pfA1 = *(const bf16x8*)(pbA + swz1);
        const bf16x8 pfB0 = *(const bf16x8*)(pbB + swz0);
        const bf16x8 pfB1 = *(const bf16x8*)(pbB + swz1);
        __builtin_amdgcn_s_setprio(1);
        #pragma unroll
        for (int db = 0; db < 4; ++db) {
            const nbf16* vr = &VT[cur][db * 16 + l15][0];
            const bf16x8 vf0 = *(const bf16x8*)(vr + swz0);
            const bf16x8 vf1 = *(const bf16x8*)(vr + swz1);
            oA[db] = __builtin_amdgcn_mfma_f32_16x16x32_bf16(pfA0, vf0, oA[db], 0, 0, 0);
            oA[db] = __builtin_amdgcn_mfma_f32_16x16x32_bf16(pfA1, vf1, oA[db], 0, 0, 0);
            oB[db] = __builtin_amdgcn_mfma_f32_16x16x32_bf16(pfB0, vf0, oB[db], 0, 0, 0);
            oB[db] = __builtin_amdgcn_mfma_f32_16x16x32_bf16(pfB1, vf1, oB[db], 0, 0, 0);
        }
        osumA = __builtin_amdgcn_mfma_f32_16x16x32_bf16(pfA0, ones, osumA, 0, 0, 0);
        osumA = __builtin_amdgcn_mfma_f32_16x16x32_bf16(pfA1, ones, osumA, 0, 0, 0);
        osumB = __builtin_amdgcn_mfma_f32_16x16x32_bf16(pfB0, ones, osumB, 0, 0, 0);
        osumB = __builtin_amdgcn_mfma_f32_16x16x32_bf16(pfB1, ones, osumB, 0, 0, 0);
        __builtin_amdgcn_s_setprio(0);

        if (t + 1 < NT) VWRITE(cur ^ 1);
        __syncthreads();
    }

    if (!SPLIT) {
        // ---- r9-proven epilogue: normalize in-kernel, write cbuf ----
        const int b = bh >> 4, h = bh & 15;
        #pragma unroll
        for (int db = 0; db < 4; ++db) {
            #pragma unroll
            for (int r = 0; r < 4; ++r) {
                const int qA = qbase + lg * 4 + r;
                cg[((size_t)(b * SEQ + qA)) * D_MODEL + h * HDK + db * 16 + l15] =
                    (nbf16)(oA[db][r] / osumA[r]);
                const int qB_ = qbase + 16 + lg * 4 + r;
                cg[((size_t)(b * SEQ + qB_)) * D_MODEL + h * HDK + db * 16 + l15] =
                    (nbf16)(oB[db][r] / osumB[r]);
            }
        }
    } else {
        // ---- split epilogue: unnormalized f32 partials + per-q {m, osum} ----
        float mvA[4], mvB[4];
        #pragma unroll
        for (int r = 0; r < 4; ++r) {
            mvA[r] = __shfl(m2A, lg * 4 + r, 64);
            mvB[r] = __shfl(m2B, lg * 4 + r, 64);
        }
        const int p = (bh * 16 + qt) * 2 + half;
        float* po = part_o + (size_t)p * (128 * 64);
        #pragma unroll
        for (int db = 0; db < 4; ++db) {
            #pragma unroll
            for (int r = 0; r < 4; ++r) {
                po[(wid * 32 + lg * 4 + r) * 64 + db * 16 + l15]      = oA[db][r];
                po[(wid * 32 + 16 + lg * 4 + r) * 64 + db * 16 + l15] = oB[db][r];
            }
        }
        if (l15 == 0) {
            #pragma unroll
            for (int r = 0; r < 4; ++r) {
                part_ms[(size_t)p * 128 + wid * 32 + lg * 4 + r]      =
                    make_float2(mvA[r], osumA[r]);
                part_ms[(size_t)p * 128 + wid * 32 + 16 + lg * 4 + r] =
                    make_float2(mvB[r], osumB[r]);
            }
        }
    }
    #undef STAGEK
    #undef VLOAD
    #undef VWRITE
    #undef SOFTMAX
}

// ---------------------------------------------------------------------------
// Combine the two kv-half partials: exact reference-max reassociation.
// ---------------------------------------------------------------------------
__global__ void attn_combine(const float* __restrict__ part_o,
                             const float2* __restrict__ part_ms,
                             nbf16* __restrict__ cg) {
    const int bq = blockIdx.x;           // bh*16 + qt
    const int bh = bq >> 4, qt = bq & 15;
    const int p0 = bq * 2, p1 = bq * 2 + 1;
    const int q  = threadIdx.x >> 1;     // 0..127
    const int d0 = (threadIdx.x & 1) * 32;

    const float2 s1 = part_ms[(size_t)p0 * 128 + q];
    const float2 s2 = part_ms[(size_t)p1 * 128 + q];
    const float m  = fmaxf(s1.x, s2.x);
    const float w1 = exp2f(s1.x - m);
    const float w2 = exp2f(s2.x - m);
    const float inv = 1.f / (s1.y * w1 + s2.y * w2);

    const float* o1 = part_o + (size_t)p0 * (128 * 64) + q * 64 + d0;
    const float* o2 = part_o + (size_t)p1 * (128 * 64) + q * 64 + d0;
    const int b = bh >> 4, h = bh & 15;
    nbf16* out = cg + ((size_t)(b * SEQ + qt * 128 + q)) * D_MODEL + h * HDK + d0;
    #pragma unroll
    for (int j = 0; j < 8; ++j) {
        const float4 a = *(const float4*)(o1 + j * 4);
        const float4 c = *(const float4*)(o2 + j * 4);
        out[j * 4 + 0] = (nbf16)((a.x * w1 + c.x * w2) * inv);
        out[j * 4 + 1] = (nbf16)((a.y * w1 + c.y * w2) * inv);
        out[j * 4 + 2] = (nbf16)((a.z * w1 + c.z * w2) * inv);
        out[j * 4 + 3] = (nbf16)((a.w * w1 + c.w * w2) * inv);
    }
}

// ---------------------------------------------------------------------------
extern "C" void kernel_launch(void* const* d_in, const int* in_sizes, int n_in,
                              void* d_out, int out_size, void* d_ws, size_t ws_size,
                              hipStream_t stream) {
    const void* X  = d_in[0];
    const void* Y  = d_in[1];
    const void* qW = d_in[2];
    const void* qB = d_in[3];
    const void* kW = d_in[4];
    const void* kB = d_in[5];
    const void* vW = d_in[6];
    const void* vB = d_in[7];
    const void* oW = d_in[8];
    const void* oB = d_in[9];

    // ---- workspace layout (proven 56MB base; split partials only if room) ----
    nbf16* ws = (nbf16*)d_ws;
    nbf16* qbuf = ws;                  // 8 MB each
    nbf16* kbuf = qbuf + QSZ;
    nbf16* vbuf = kbuf + QSZ;
    nbf16* cbuf = vbuf + QSZ;
    nbf16* Xb   = cbuf + QSZ;
    nbf16* Yb   = Xb + QSZ;
    nbf16* Wt3  = Yb + QSZ;            // 6 MB
    nbf16* Wto  = Wt3 + 3 * WSZ;       // 2 MB
    int*   flag = (int*)(Wto + WSZ);
    char*  pbase = (char*)flag + 256;
    float2* part_ms = (float2*)pbase;                          // 1 MB
    float*  part_o  = (float*)(part_ms + (size_t)1024 * 128);  // 32 MB
    const size_t need_split =
        (size_t)((char*)(part_o + (size_t)1024 * 128 * 64) - (char*)d_ws);
    const bool use_split = (ws_size >= need_split);   // r10 lesson: CHECK.

    detect_dtype<<<1, 256, 0, stream>>>((const unsigned short*)X, flag);

    prep<<<5120, 256, 0, stream>>>(X, Y, qW, kW, vW, oW, Xb, Yb, Wt3, Wto, flag);

    proj_qkv<<<768, 256, 0, stream>>>(Xb, Yb, Wt3, qB, kB, vB, qbuf, flag);

    if (use_split) {
        attn_mfma<true><<<1024, 256, 0, stream>>>(qbuf, kbuf, vbuf, cbuf,
                                                  part_o, part_ms);
        attn_combine<<<512, 256, 0, stream>>>(part_o, part_ms, cbuf);
    } else {
        attn_mfma<false><<<512, 256, 0, stream>>>(qbuf, kbuf, vbuf, cbuf,
                                                  nullptr, nullptr);
    }

    proj_o<<<256, 256, 0, stream>>>(cbuf, Wto, oB, d_out, flag);
}